// Round 4
// baseline (516.579 us; speedup 1.0000x reference)
//
#include <hip/hip_runtime.h>

#define BB 128
#define SS 64
#define KK 10
#define DD 256
#define NN (BB*SS)        // 8192 rows
#define ROWS 32           // rows per block
#define NBLK (NN/ROWS)    // 256 blocks = 1 per CU
#define NT 1024           // 16 waves per block -> 4 waves/SIMD

typedef __attribute__((ext_vector_type(8))) short short8;
typedef __attribute__((ext_vector_type(4))) float f32x4;

#define FRAG_ELEMS (48*8*64*8)   // 196608 bf16 values per weight matrix

__device__ __forceinline__ unsigned short f2bf(float f){
  union { float f; unsigned u; } v; v.f = f;
  unsigned r = (v.u + 0x7FFFu + ((v.u >> 16) & 1u)) >> 16;
  return (unsigned short)r;
}

// LDS-only barrier: drain ds ops, leave global loads in flight.
// (__syncthreads would emit s_waitcnt vmcnt(0) and kill the weight pipeline.)
__device__ __forceinline__ void lds_barrier(){
  asm volatile("s_waitcnt lgkmcnt(0)\n\ts_barrier" ::: "memory");
}

// Pre-swizzle W_ih[:, :D] and W_hh into bf16 MFMA B-fragment order:
// frag value at (tn, tk, lane, j) = W[c = tn*16 + (lane&15)][d = tk*32 + (lane>>4)*8 + j]
// stored flat at ((tn*8+tk)*64 + lane)*8 + j.  FW1 first, FWhh second.
__global__ void prep_weights(const float* __restrict__ Wih,
                             const float* __restrict__ Whh,
                             unsigned short* __restrict__ fw){
  int id = blockIdx.x * 256 + threadIdx.x;     // 0 .. 2*FRAG_ELEMS-1
  int arr = (id >= FRAG_ELEMS);
  int r = arr ? (id - FRAG_ELEMS) : id;
  int j  = r & 7;
  int l  = (r >> 3) & 63;
  int tk = (r >> 9) & 7;
  int tn = r >> 12;                            // 0..47
  int c  = tn * 16 + (l & 15);                 // 0..767
  int d  = tk * 32 + ((l >> 4) << 3) + j;      // 0..255
  float v = arr ? Whh[c * 256 + d] : Wih[c * 512 + d];
  fw[id] = f2bf(v);
}

__global__ __launch_bounds__(NT, 4) void gru_main(
    const float* __restrict__ item, const float* __restrict__ user,
    const float* __restrict__ b_ih, const float* __restrict__ b_hh,
    const float* __restrict__ w_out, const float* __restrict__ b_out,
    const int* __restrict__ length, const unsigned short* __restrict__ ws,
    float* __restrict__ out)
{
  // A-fragment layout: elem (mt, tk, lane, j) at ((mt*8+tk)*64+lane)*8+j
  __shared__ unsigned short xfrag[2][2*8*64*8];   // 32 KB
  __shared__ unsigned short hfrag[2][2*8*64*8];   // 32 KB
  __shared__ float yp[3][16][2][4][4];            // 6 KB, triple-buffered

  const int tid  = threadIdx.x;
  const int lane = tid & 63;
  const int w    = tid >> 6;        // wave 0..15 == column group g
  const int col  = lane & 15;       // C-layout col
  const int q    = lane >> 4;       // quad
  const int nb   = blockIdx.x * ROWS;
  const int b    = nb / SS;         // one user per block

  const short8* fw1 = (const short8*)ws;
  const short8* fwh = fw1 + (FRAG_ELEMS/8);

  // per-matrix fragment base pointers for this wave's group (element tk at [tk*64])
  const short8* wbase0 = fw1 + (size_t)((w     )*8)*64 + lane;
  const short8* wbase1 = fw1 + (size_t)((16 + w)*8)*64 + lane;
  const short8* wbase2 = fw1 + (size_t)((32 + w)*8)*64 + lane;
  const short8* wbase3 = fwh + (size_t)((w     )*8)*64 + lane;
  const short8* wbase4 = fwh + (size_t)((16 + w)*8)*64 + lane;
  const short8* wbase5 = fwh + (size_t)((32 + w)*8)*64 + lane;

  // per-column constants (this thread owns output channel d for 8 rows)
  const int d    = w*16 + col;
  const float br_  = b_ih[d]       + b_hh[d];
  const float bz_  = b_ih[256 + d] + b_hh[256 + d];
  const float bin_ = b_ih[512 + d];
  const float bhn_ = b_hh[512 + d];
  const float wo_  = w_out[d];

  // h0 = user_embs[b, clip(length[b]-1,0)]; identical for all 32 rows
  int idx = length[b] - 1; if (idx < 0) idx = 0;
  const float u0 = user[((size_t)b*SS + idx)*DD + d];
  float h[2][4];
  #pragma unroll
  for (int mt = 0; mt < 2; ++mt)
    #pragma unroll
    for (int reg = 0; reg < 4; ++reg)
      h[mt][reg] = u0;

  // write h0 into hfrag[0] (A-fragment layout), owner-thread scatter
  const int tkk = d >> 5;
  const int slb = ((d >> 3) & 3) * 16;
  const int dj  = d & 7;
  {
    unsigned short hb = f2bf(u0);
    #pragma unroll
    for (int mt = 0; mt < 2; ++mt)
      #pragma unroll
      for (int reg = 0; reg < 4; ++reg)
        hfrag[0][((mt*8 + tkk)*64 + slb + q*4 + reg)*8 + dj] = hb;
  }

  // cooperative x-tile load: thread covers row = tid>>5, 8 d's at (tid&31)*8
  const int xrow = tid >> 5;        // 0..31
  const int xo   = tid & 31;        // which 8-wide d chunk
  const int xmt  = xrow >> 4;
  const int xtk  = xo >> 2;
  const int xsl  = (xo & 3)*16 + (xrow & 15);
  {
    const float4* p = (const float4*)(item + ((size_t)(nb + xrow)*KK + 0)*DD + xo*8);
    float4 a0 = p[0], a1 = p[1];
    unsigned short t[8];
    t[0]=f2bf(a0.x); t[1]=f2bf(a0.y); t[2]=f2bf(a0.z); t[3]=f2bf(a0.w);
    t[4]=f2bf(a1.x); t[5]=f2bf(a1.y); t[6]=f2bf(a1.z); t[7]=f2bf(a1.w);
    *(short8*)&xfrag[0][((xmt*8 + xtk)*64 + xsl)*8] = *(short8*)t;
  }

  // weight pipeline prologue: batches 0 and 1 in flight
  short8 Wb[2][6];
  #pragma unroll
  for (int s = 0; s < 2; ++s){
    Wb[s][0] = wbase0[s*64];
    Wb[s][1] = wbase1[s*64];
    Wb[s][2] = wbase2[s*64];
    Wb[s][3] = wbase3[s*64];
    Wb[s][4] = wbase4[s*64];
    Wb[s][5] = wbase5[s*64];
  }

  lds_barrier();

  const float bout = b_out[0];

  for (int k = 0; k < KK; ++k){
    const int cb  = k & 1;
    const int nbf = cb ^ 1;

    // x prefetch for next step — issue first, consume in the tail
    float4 xn0, xn1;
    if (k < KK-1){
      const float4* p = (const float4*)(item + ((size_t)(nb + xrow)*KK + (k+1))*DD + xo*8);
      xn0 = p[0]; xn1 = p[1];
    }

    // accumulators: [mt][kind]  kind: 0=r 1=z 2=i_n 3=h_n
    f32x4 acc[2][4];
    #pragma unroll
    for (int mt = 0; mt < 2; ++mt)
      #pragma unroll
      for (int kd = 0; kd < 4; ++kd){
        f32x4 z4 = {0.f, 0.f, 0.f, 0.f};
        acc[mt][kd] = z4;
      }

    #pragma unroll
    for (int tk = 0; tk < 8; ++tk){
      const int slot = tk & 1;
      // consume current batch into locals
      short8 w1r = Wb[slot][0], w1z = Wb[slot][1], w1n = Wb[slot][2];
      short8 whr = Wb[slot][3], whz = Wb[slot][4], whn = Wb[slot][5];
      // refill slot with batch (tk+2)&7 — at tk=6,7 this loads NEXT step's
      // batches 0,1 (same addresses every step); they stay in flight across
      // the lds_barrier.
      const int nx = (tk + 2) & 7;
      Wb[slot][0] = wbase0[nx*64];
      Wb[slot][1] = wbase1[nx*64];
      Wb[slot][2] = wbase2[nx*64];
      Wb[slot][3] = wbase3[nx*64];
      Wb[slot][4] = wbase4[nx*64];
      Wb[slot][5] = wbase5[nx*64];

      short8 ax0 = *(const short8*)&xfrag[cb][((0*8 + tk)*64 + lane)*8];
      short8 ax1 = *(const short8*)&xfrag[cb][((1*8 + tk)*64 + lane)*8];
      short8 ah0 = *(const short8*)&hfrag[cb][((0*8 + tk)*64 + lane)*8];
      short8 ah1 = *(const short8*)&hfrag[cb][((1*8 + tk)*64 + lane)*8];

      acc[0][0] = __builtin_amdgcn_mfma_f32_16x16x32_bf16(ax0, w1r, acc[0][0], 0, 0, 0);
      acc[1][0] = __builtin_amdgcn_mfma_f32_16x16x32_bf16(ax1, w1r, acc[1][0], 0, 0, 0);
      acc[0][0] = __builtin_amdgcn_mfma_f32_16x16x32_bf16(ah0, whr, acc[0][0], 0, 0, 0);
      acc[1][0] = __builtin_amdgcn_mfma_f32_16x16x32_bf16(ah1, whr, acc[1][0], 0, 0, 0);
      acc[0][1] = __builtin_amdgcn_mfma_f32_16x16x32_bf16(ax0, w1z, acc[0][1], 0, 0, 0);
      acc[1][1] = __builtin_amdgcn_mfma_f32_16x16x32_bf16(ax1, w1z, acc[1][1], 0, 0, 0);
      acc[0][1] = __builtin_amdgcn_mfma_f32_16x16x32_bf16(ah0, whz, acc[0][1], 0, 0, 0);
      acc[1][1] = __builtin_amdgcn_mfma_f32_16x16x32_bf16(ah1, whz, acc[1][1], 0, 0, 0);
      acc[0][2] = __builtin_amdgcn_mfma_f32_16x16x32_bf16(ax0, w1n, acc[0][2], 0, 0, 0);
      acc[1][2] = __builtin_amdgcn_mfma_f32_16x16x32_bf16(ax1, w1n, acc[1][2], 0, 0, 0);
      acc[0][3] = __builtin_amdgcn_mfma_f32_16x16x32_bf16(ah0, whn, acc[0][3], 0, 0, 0);
      acc[1][3] = __builtin_amdgcn_mfma_f32_16x16x32_bf16(ah1, whn, acc[1][3], 0, 0, 0);
    }

    // gates — entirely in-register
    float ypl[2][4];
    #pragma unroll
    for (int mt = 0; mt < 2; ++mt)
      #pragma unroll
      for (int reg = 0; reg < 4; ++reg){
        float rp = acc[mt][0][reg] + br_;
        float zp = acc[mt][1][reg] + bz_;
        float r  = 1.f / (1.f + __expf(-rp));
        float z  = 1.f / (1.f + __expf(-zp));
        float np = acc[mt][2][reg] + bin_ + r*(acc[mt][3][reg] + bhn_);
        np = fminf(fmaxf(np, -30.f), 30.f);
        float e  = __expf(2.f*np);
        float n  = (e - 1.f) / (e + 1.f);     // tanh
        float hv = (1.f - z)*n + z*h[mt][reg];
        h[mt][reg] = hv;
        ypl[mt][reg] = hv * wo_;
      }

    // y partial: reduce across the 16 cols of this wave's group
    #pragma unroll
    for (int mt = 0; mt < 2; ++mt)
      #pragma unroll
      for (int reg = 0; reg < 4; ++reg){
        float p = ypl[mt][reg];
        p += __shfl_xor(p, 1);
        p += __shfl_xor(p, 2);
        p += __shfl_xor(p, 4);
        p += __shfl_xor(p, 8);
        if (col == 0) yp[k % 3][w][mt][q][reg] = p;
      }

    // write h' (bf16) into hfrag[nbf] for next step
    #pragma unroll
    for (int mt = 0; mt < 2; ++mt)
      #pragma unroll
      for (int reg = 0; reg < 4; ++reg)
        hfrag[nbf][((mt*8 + tkk)*64 + slb + q*4 + reg)*8 + dj] = f2bf(h[mt][reg]);

    // write next x tile into xfrag[nbf]
    if (k < KK-1){
      unsigned short t[8];
      t[0]=f2bf(xn0.x); t[1]=f2bf(xn0.y); t[2]=f2bf(xn0.z); t[3]=f2bf(xn0.w);
      t[4]=f2bf(xn1.x); t[5]=f2bf(xn1.y); t[6]=f2bf(xn1.z); t[7]=f2bf(xn1.w);
      *(short8*)&xfrag[nbf][((xmt*8 + xtk)*64 + xsl)*8] = *(short8*)t;
    }

    // finalize y for step k-1 (yp[(k-1)%3] stable since previous barrier)
    if (k > 0 && tid < 32){
      float s = bout;
      #pragma unroll
      for (int ww = 0; ww < 16; ++ww)
        s += yp[(k-1) % 3][ww][tid >> 4][(tid >> 2) & 3][tid & 3];
      out[(size_t)(nb + tid)*KK + (k-1)] = s;
    }

    lds_barrier();   // LDS-only: weight loads for next step stay in flight
  }

  // finalize y for the last step
  if (tid < 32){
    float s = bout;
    #pragma unroll
    for (int ww = 0; ww < 16; ++ww)
      s += yp[(KK-1) % 3][ww][tid >> 4][(tid >> 2) & 3][tid & 3];
    out[(size_t)(nb + tid)*KK + (KK-1)] = s;
  }
}

extern "C" void kernel_launch(void* const* d_in, const int* in_sizes, int n_in,
                              void* d_out, int out_size, void* d_ws, size_t ws_size,
                              hipStream_t stream) {
  const float* item   = (const float*)d_in[0];
  const float* user   = (const float*)d_in[1];
  const float* W_ih   = (const float*)d_in[2];
  const float* W_hh   = (const float*)d_in[3];
  const float* b_ih   = (const float*)d_in[4];
  const float* b_hh   = (const float*)d_in[5];
  const float* w_out  = (const float*)d_in[6];
  const float* b_out  = (const float*)d_in[7];
  const int*   length = (const int*)d_in[8];
  unsigned short* ws  = (unsigned short*)d_ws;   // needs 768 KB
  float* out = (float*)d_out;

  hipLaunchKernelGGL(prep_weights, dim3((2*FRAG_ELEMS)/256), dim3(256), 0, stream,
                     W_ih, W_hh, ws);
  hipLaunchKernelGGL(gru_main, dim3(NBLK), dim3(NT), 0, stream,
                     item, user, b_ih, b_hh, w_out, b_out, length, ws, out);
}

// Round 5
// 487.306 us; speedup vs baseline: 1.0601x; 1.0601x over previous
//
#include <hip/hip_runtime.h>

#define BB 128
#define SS 64
#define KK 10
#define DD 256
#define NN (BB*SS)        // 8192 rows
#define ROWS 32           // rows per block
#define NBLK (NN/ROWS)    // 256 blocks = 1 per CU
#define NT 1024           // 16 waves per block -> 4 waves/SIMD
#define NSUP (KK/2)       // 5 super-steps of 2

typedef __attribute__((ext_vector_type(8))) short short8;
typedef __attribute__((ext_vector_type(4))) float f32x4;

#define FRAG_ELEMS (48*8*64*8)   // 196608 bf16 values per weight matrix

__device__ __forceinline__ unsigned short f2bf(float f){
  union { float f; unsigned u; } v; v.f = f;
  unsigned r = (v.u + 0x7FFFu + ((v.u >> 16) & 1u)) >> 16;
  return (unsigned short)r;
}
__device__ __forceinline__ unsigned packbf2(float a, float b){
  return (unsigned)f2bf(a) | ((unsigned)f2bf(b) << 16);
}
__device__ __forceinline__ float unpacklo(unsigned p){
  union { unsigned u; float f; } v; v.u = p << 16; return v.f;
}
__device__ __forceinline__ float unpackhi(unsigned p){
  union { unsigned u; float f; } v; v.u = p & 0xffff0000u; return v.f;
}

// Pre-swizzle W_ih[:, :D] and W_hh into bf16 MFMA B-fragment order:
// frag value at (tn, tk, lane, j) = W[c = tn*16 + (lane&15)][d = tk*32 + (lane>>4)*8 + j]
// stored flat at ((tn*8+tk)*64 + lane)*8 + j.  FW1 first, FWhh second.
__global__ void prep_weights(const float* __restrict__ Wih,
                             const float* __restrict__ Whh,
                             unsigned short* __restrict__ fw){
  int id = blockIdx.x * 256 + threadIdx.x;     // 0 .. 2*FRAG_ELEMS-1
  int arr = (id >= FRAG_ELEMS);
  int r = arr ? (id - FRAG_ELEMS) : id;
  int j  = r & 7;
  int l  = (r >> 3) & 63;
  int tk = (r >> 9) & 7;
  int tn = r >> 12;                            // 0..47
  int c  = tn * 16 + (l & 15);                 // 0..767
  int d  = tk * 32 + ((l >> 4) << 3) + j;      // 0..255
  float v = arr ? Whh[c * 256 + d] : Wih[c * 512 + d];
  fw[id] = f2bf(v);
}

__global__ __launch_bounds__(NT, 4) void gru_main(
    const float* __restrict__ item, const float* __restrict__ user,
    const float* __restrict__ b_ih, const float* __restrict__ b_hh,
    const float* __restrict__ w_out, const float* __restrict__ b_out,
    const int* __restrict__ length, const unsigned short* __restrict__ ws,
    float* __restrict__ out)
{
  // A-fragment layout: elem (mt, tk, lane, j) at ((mt*8+tk)*64+lane)*8+j
  __shared__ unsigned short xs[2][2][2*8*64*8];  // [superstep-buf][step], 64 KB
  __shared__ unsigned short hfrag[2][2*8*64*8];  // ping-pong within superstep, 32 KB
  __shared__ float yp[3][16][2][4][4];           // 6 KB, triple-buffered

  const int tid  = threadIdx.x;
  const int lane = tid & 63;
  const int w    = tid >> 6;        // wave 0..15 == column group g
  const int col  = lane & 15;       // C-layout col
  const int q    = lane >> 4;       // quad
  const int nb   = blockIdx.x * ROWS;
  const int b    = nb / SS;         // one user per block

  const short8* fw1 = (const short8*)ws;
  const short8* fwh = fw1 + (FRAG_ELEMS/8);

  // per-column constants (this thread owns output channel d for 8 rows)
  const int d    = w*16 + col;
  const float br_  = b_ih[d]       + b_hh[d];
  const float bz_  = b_ih[256 + d] + b_hh[256 + d];
  const float bin_ = b_ih[512 + d];
  const float bhn_ = b_hh[512 + d];
  const float wo_  = w_out[d];

  // h0 = user_embs[b, clip(length[b]-1,0)]; identical for all 32 rows
  int idx = length[b] - 1; if (idx < 0) idx = 0;
  const float u0 = user[((size_t)b*SS + idx)*DD + d];
  float h[2][4];
  #pragma unroll
  for (int mt = 0; mt < 2; ++mt)
    #pragma unroll
    for (int reg = 0; reg < 4; ++reg)
      h[mt][reg] = u0;

  // write h0 into hfrag[0] (A-fragment layout), owner-thread scatter
  const int tkk = d >> 5;
  const int slb = ((d >> 3) & 3) * 16;
  const int dj  = d & 7;
  {
    unsigned short hb = f2bf(u0);
    #pragma unroll
    for (int mt = 0; mt < 2; ++mt)
      #pragma unroll
      for (int reg = 0; reg < 4; ++reg)
        hfrag[0][((mt*8 + tkk)*64 + slb + q*4 + reg)*8 + dj] = hb;
  }

  // cooperative x staging geometry: thread covers row = tid>>5, 8 d's at (tid&31)*8
  const int xrow = tid >> 5;        // 0..31
  const int xo   = tid & 31;        // which 8-wide d chunk
  const int xmt  = xrow >> 4;
  const int xtk  = xo >> 2;
  const int xsl  = (xo & 3)*16 + (xrow & 15);
  const int xdst = ((xmt*8 + xtk)*64 + xsl)*8;

  // prologue: stage x for steps 0 and 1 into xs[0][0], xs[0][1]
  #pragma unroll
  for (int s = 0; s < 2; ++s){
    const float4* p = (const float4*)(item + ((size_t)(nb + xrow)*KK + s)*DD + xo*8);
    float4 a0 = p[0], a1 = p[1];
    unsigned short t[8];
    t[0]=f2bf(a0.x); t[1]=f2bf(a0.y); t[2]=f2bf(a0.z); t[3]=f2bf(a0.w);
    t[4]=f2bf(a1.x); t[5]=f2bf(a1.y); t[6]=f2bf(a1.z); t[7]=f2bf(a1.w);
    *(short8*)&xs[0][s][xdst] = *(short8*)t;
  }
  __syncthreads();

  const float bout = b_out[0];

  for (int j = 0; j < NSUP; ++j){
    const int k0  = 2*j;
    const int k1  = 2*j + 1;
    const int cb  = j & 1;
    const int nbf = cb ^ 1;

    // ---------------- phase A: gi for both steps, one W1 pass ----------------
    f32x4 g0[2][3];   // step k0: [mt][gate r,z,n]
    f32x4 g1[2][3];   // step k1
    #pragma unroll
    for (int mt = 0; mt < 2; ++mt)
      #pragma unroll
      for (int g = 0; g < 3; ++g){
        f32x4 z4 = {0.f,0.f,0.f,0.f};
        g0[mt][g] = z4; g1[mt][g] = z4;
      }

    #pragma unroll
    for (int tk = 0; tk < 8; ++tk){
      short8 w1r = fw1[((w     )*8 + tk)*64 + lane];
      short8 w1z = fw1[((16 + w)*8 + tk)*64 + lane];
      short8 w1n = fw1[((32 + w)*8 + tk)*64 + lane];
      short8 a00 = *(const short8*)&xs[cb][0][((0*8 + tk)*64 + lane)*8];
      short8 a01 = *(const short8*)&xs[cb][0][((1*8 + tk)*64 + lane)*8];
      short8 a10 = *(const short8*)&xs[cb][1][((0*8 + tk)*64 + lane)*8];
      short8 a11 = *(const short8*)&xs[cb][1][((1*8 + tk)*64 + lane)*8];
      g0[0][0] = __builtin_amdgcn_mfma_f32_16x16x32_bf16(a00, w1r, g0[0][0], 0, 0, 0);
      g0[1][0] = __builtin_amdgcn_mfma_f32_16x16x32_bf16(a01, w1r, g0[1][0], 0, 0, 0);
      g1[0][0] = __builtin_amdgcn_mfma_f32_16x16x32_bf16(a10, w1r, g1[0][0], 0, 0, 0);
      g1[1][0] = __builtin_amdgcn_mfma_f32_16x16x32_bf16(a11, w1r, g1[1][0], 0, 0, 0);
      g0[0][1] = __builtin_amdgcn_mfma_f32_16x16x32_bf16(a00, w1z, g0[0][1], 0, 0, 0);
      g0[1][1] = __builtin_amdgcn_mfma_f32_16x16x32_bf16(a01, w1z, g0[1][1], 0, 0, 0);
      g1[0][1] = __builtin_amdgcn_mfma_f32_16x16x32_bf16(a10, w1z, g1[0][1], 0, 0, 0);
      g1[1][1] = __builtin_amdgcn_mfma_f32_16x16x32_bf16(a11, w1z, g1[1][1], 0, 0, 0);
      g0[0][2] = __builtin_amdgcn_mfma_f32_16x16x32_bf16(a00, w1n, g0[0][2], 0, 0, 0);
      g0[1][2] = __builtin_amdgcn_mfma_f32_16x16x32_bf16(a01, w1n, g0[1][2], 0, 0, 0);
      g1[0][2] = __builtin_amdgcn_mfma_f32_16x16x32_bf16(a10, w1n, g1[0][2], 0, 0, 0);
      g1[1][2] = __builtin_amdgcn_mfma_f32_16x16x32_bf16(a11, w1n, g1[1][2], 0, 0, 0);
    }

    // park k1's gi as packed bf16 (frees 12 VGPRs before phase B)
    unsigned p1[2][3][2];
    #pragma unroll
    for (int mt = 0; mt < 2; ++mt)
      #pragma unroll
      for (int g = 0; g < 3; ++g){
        p1[mt][g][0] = packbf2(g1[mt][g][0], g1[mt][g][1]);
        p1[mt][g][1] = packbf2(g1[mt][g][2], g1[mt][g][3]);
      }

    // ---------------- phase B: step k0 (gh, gates) ----------------
    {
      f32x4 gh[2][3];
      #pragma unroll
      for (int mt = 0; mt < 2; ++mt)
        #pragma unroll
        for (int g = 0; g < 3; ++g){
          f32x4 z4 = {0.f,0.f,0.f,0.f};
          gh[mt][g] = z4;
        }
      #pragma unroll
      for (int tk = 0; tk < 8; ++tk){
        short8 whr = fwh[((w     )*8 + tk)*64 + lane];
        short8 whz = fwh[((16 + w)*8 + tk)*64 + lane];
        short8 whn = fwh[((32 + w)*8 + tk)*64 + lane];
        short8 ah0 = *(const short8*)&hfrag[0][((0*8 + tk)*64 + lane)*8];
        short8 ah1 = *(const short8*)&hfrag[0][((1*8 + tk)*64 + lane)*8];
        gh[0][0] = __builtin_amdgcn_mfma_f32_16x16x32_bf16(ah0, whr, gh[0][0], 0, 0, 0);
        gh[1][0] = __builtin_amdgcn_mfma_f32_16x16x32_bf16(ah1, whr, gh[1][0], 0, 0, 0);
        gh[0][1] = __builtin_amdgcn_mfma_f32_16x16x32_bf16(ah0, whz, gh[0][1], 0, 0, 0);
        gh[1][1] = __builtin_amdgcn_mfma_f32_16x16x32_bf16(ah1, whz, gh[1][1], 0, 0, 0);
        gh[0][2] = __builtin_amdgcn_mfma_f32_16x16x32_bf16(ah0, whn, gh[0][2], 0, 0, 0);
        gh[1][2] = __builtin_amdgcn_mfma_f32_16x16x32_bf16(ah1, whn, gh[1][2], 0, 0, 0);
      }

      // x prefetch for step k0+2 (L3-resident; covered by gates below)
      float4 xb0, xb1;
      if (j < NSUP-1){
        const float4* p = (const float4*)(item + ((size_t)(nb + xrow)*KK + (k0+2))*DD + xo*8);
        xb0 = p[0]; xb1 = p[1];
      }

      // gates k0
      float ypl[2][4];
      #pragma unroll
      for (int mt = 0; mt < 2; ++mt)
        #pragma unroll
        for (int reg = 0; reg < 4; ++reg){
          float rp = g0[mt][0][reg] + gh[mt][0][reg] + br_;
          float zp = g0[mt][1][reg] + gh[mt][1][reg] + bz_;
          float r  = 1.f / (1.f + __expf(-rp));
          float z  = 1.f / (1.f + __expf(-zp));
          float np = g0[mt][2][reg] + bin_ + r*(gh[mt][2][reg] + bhn_);
          np = fminf(fmaxf(np, -30.f), 30.f);
          float e  = __expf(2.f*np);
          float n  = (e - 1.f) / (e + 1.f);
          float hv = (1.f - z)*n + z*h[mt][reg];
          h[mt][reg] = hv;
          ypl[mt][reg] = hv * wo_;
        }

      #pragma unroll
      for (int mt = 0; mt < 2; ++mt)
        #pragma unroll
        for (int reg = 0; reg < 4; ++reg){
          float p = ypl[mt][reg];
          p += __shfl_xor(p, 1);
          p += __shfl_xor(p, 2);
          p += __shfl_xor(p, 4);
          p += __shfl_xor(p, 8);
          if (col == 0) yp[k0 % 3][w][mt][q][reg] = p;
        }

      // h_{k0+1} -> hfrag[1]
      #pragma unroll
      for (int mt = 0; mt < 2; ++mt)
        #pragma unroll
        for (int reg = 0; reg < 4; ++reg)
          hfrag[1][((mt*8 + tkk)*64 + slb + q*4 + reg)*8 + dj] = f2bf(h[mt][reg]);

      // stage x_{k0+2} into xs[nbf][0]
      if (j < NSUP-1){
        unsigned short t[8];
        t[0]=f2bf(xb0.x); t[1]=f2bf(xb0.y); t[2]=f2bf(xb0.z); t[3]=f2bf(xb0.w);
        t[4]=f2bf(xb1.x); t[5]=f2bf(xb1.y); t[6]=f2bf(xb1.z); t[7]=f2bf(xb1.w);
        *(short8*)&xs[nbf][0][xdst] = *(short8*)t;
      }

      // finalize y for step k0-1
      if (j > 0 && tid < 32){
        float s = bout;
        #pragma unroll
        for (int ww = 0; ww < 16; ++ww)
          s += yp[(k0-1) % 3][ww][tid >> 4][(tid >> 2) & 3][tid & 3];
        out[(size_t)(nb + tid)*KK + (k0-1)] = s;
      }
    }
    __syncthreads();   // mid barrier: h_{k0+1} visible

    // ---------------- phase C: step k1 (gh, gates) ----------------
    {
      f32x4 gh[2][3];
      #pragma unroll
      for (int mt = 0; mt < 2; ++mt)
        #pragma unroll
        for (int g = 0; g < 3; ++g){
          f32x4 z4 = {0.f,0.f,0.f,0.f};
          gh[mt][g] = z4;
        }
      #pragma unroll
      for (int tk = 0; tk < 8; ++tk){
        short8 whr = fwh[((w     )*8 + tk)*64 + lane];
        short8 whz = fwh[((16 + w)*8 + tk)*64 + lane];
        short8 whn = fwh[((32 + w)*8 + tk)*64 + lane];
        short8 ah0 = *(const short8*)&hfrag[1][((0*8 + tk)*64 + lane)*8];
        short8 ah1 = *(const short8*)&hfrag[1][((1*8 + tk)*64 + lane)*8];
        gh[0][0] = __builtin_amdgcn_mfma_f32_16x16x32_bf16(ah0, whr, gh[0][0], 0, 0, 0);
        gh[1][0] = __builtin_amdgcn_mfma_f32_16x16x32_bf16(ah1, whr, gh[1][0], 0, 0, 0);
        gh[0][1] = __builtin_amdgcn_mfma_f32_16x16x32_bf16(ah0, whz, gh[0][1], 0, 0, 0);
        gh[1][1] = __builtin_amdgcn_mfma_f32_16x16x32_bf16(ah1, whz, gh[1][1], 0, 0, 0);
        gh[0][2] = __builtin_amdgcn_mfma_f32_16x16x32_bf16(ah0, whn, gh[0][2], 0, 0, 0);
        gh[1][2] = __builtin_amdgcn_mfma_f32_16x16x32_bf16(ah1, whn, gh[1][2], 0, 0, 0);
      }

      // x prefetch for step k1+2
      float4 xb0, xb1;
      if (j < NSUP-1){
        const float4* p = (const float4*)(item + ((size_t)(nb + xrow)*KK + (k1+2))*DD + xo*8);
        xb0 = p[0]; xb1 = p[1];
      }

      // gates k1 (unpack parked gi)
      float ypl[2][4];
      #pragma unroll
      for (int mt = 0; mt < 2; ++mt)
        #pragma unroll
        for (int reg = 0; reg < 4; ++reg){
          unsigned pr = p1[mt][0][reg>>1];
          unsigned pz = p1[mt][1][reg>>1];
          unsigned pn = p1[mt][2][reg>>1];
          float gir = (reg & 1) ? unpackhi(pr) : unpacklo(pr);
          float giz = (reg & 1) ? unpackhi(pz) : unpacklo(pz);
          float gin = (reg & 1) ? unpackhi(pn) : unpacklo(pn);
          float rp = gir + gh[mt][0][reg] + br_;
          float zp = giz + gh[mt][1][reg] + bz_;
          float r  = 1.f / (1.f + __expf(-rp));
          float z  = 1.f / (1.f + __expf(-zp));
          float np = gin + bin_ + r*(gh[mt][2][reg] + bhn_);
          np = fminf(fmaxf(np, -30.f), 30.f);
          float e  = __expf(2.f*np);
          float n  = (e - 1.f) / (e + 1.f);
          float hv = (1.f - z)*n + z*h[mt][reg];
          h[mt][reg] = hv;
          ypl[mt][reg] = hv * wo_;
        }

      #pragma unroll
      for (int mt = 0; mt < 2; ++mt)
        #pragma unroll
        for (int reg = 0; reg < 4; ++reg){
          float p = ypl[mt][reg];
          p += __shfl_xor(p, 1);
          p += __shfl_xor(p, 2);
          p += __shfl_xor(p, 4);
          p += __shfl_xor(p, 8);
          if (col == 0) yp[k1 % 3][w][mt][q][reg] = p;
        }

      // h_{k1+1} -> hfrag[0] (read of hfrag[0] finished before mid barrier)
      #pragma unroll
      for (int mt = 0; mt < 2; ++mt)
        #pragma unroll
        for (int reg = 0; reg < 4; ++reg)
          hfrag[0][((mt*8 + tkk)*64 + slb + q*4 + reg)*8 + dj] = f2bf(h[mt][reg]);

      // stage x_{k1+2} into xs[nbf][1]
      if (j < NSUP-1){
        unsigned short t[8];
        t[0]=f2bf(xb0.x); t[1]=f2bf(xb0.y); t[2]=f2bf(xb0.z); t[3]=f2bf(xb0.w);
        t[4]=f2bf(xb1.x); t[5]=f2bf(xb1.y); t[6]=f2bf(xb1.z); t[7]=f2bf(xb1.w);
        *(short8*)&xs[nbf][1][xdst] = *(short8*)t;
      }

      // finalize y for step k0 (yp[k0%3] written before mid barrier)
      if (tid < 32){
        float s = bout;
        #pragma unroll
        for (int ww = 0; ww < 16; ++ww)
          s += yp[k0 % 3][ww][tid >> 4][(tid >> 2) & 3][tid & 3];
        out[(size_t)(nb + tid)*KK + k0] = s;
      }
    }
    __syncthreads();   // end barrier: h_{k1+1}, staged x visible
  }

  // finalize y for the last step
  if (tid < 32){
    float s = bout;
    #pragma unroll
    for (int ww = 0; ww < 16; ++ww)
      s += yp[(KK-1) % 3][ww][tid >> 4][(tid >> 2) & 3][tid & 3];
    out[(size_t)(nb + tid)*KK + (KK-1)] = s;
  }
}

extern "C" void kernel_launch(void* const* d_in, const int* in_sizes, int n_in,
                              void* d_out, int out_size, void* d_ws, size_t ws_size,
                              hipStream_t stream) {
  const float* item   = (const float*)d_in[0];
  const float* user   = (const float*)d_in[1];
  const float* W_ih   = (const float*)d_in[2];
  const float* W_hh   = (const float*)d_in[3];
  const float* b_ih   = (const float*)d_in[4];
  const float* b_hh   = (const float*)d_in[5];
  const float* w_out  = (const float*)d_in[6];
  const float* b_out  = (const float*)d_in[7];
  const int*   length = (const int*)d_in[8];
  unsigned short* ws  = (unsigned short*)d_ws;   // needs 768 KB
  float* out = (float*)d_out;

  hipLaunchKernelGGL(prep_weights, dim3((2*FRAG_ELEMS)/256), dim3(256), 0, stream,
                     W_ih, W_hh, ws);
  hipLaunchKernelGGL(gru_main, dim3(NBLK), dim3(NT), 0, stream,
                     item, user, b_ih, b_hh, w_out, b_out, length, ws, out);
}

// Round 6
// 422.917 us; speedup vs baseline: 1.2215x; 1.1523x over previous
//
#include <hip/hip_runtime.h>

#define BB 128
#define SS 64
#define KK 10
#define DD 256
#define NN (BB*SS)        // 8192 rows
#define ROWS 32           // rows per block
#define NBLK (NN/ROWS)    // 256 blocks = 1 per CU
#define NT 1024           // 16 waves per block -> 4 waves/SIMD (hard cap: 128 regs/thread)
#define NSUP (KK/2)       // 5 super-steps of 2

typedef __attribute__((ext_vector_type(8))) short short8;
typedef __attribute__((ext_vector_type(4))) float f32x4;

#define FRAG_ELEMS (48*8*64*8)   // 196608 bf16 values per weight matrix

__device__ __forceinline__ unsigned short f2bf(float f){
  union { float f; unsigned u; } v; v.f = f;
  unsigned r = (v.u + 0x7FFFu + ((v.u >> 16) & 1u)) >> 16;
  return (unsigned short)r;
}
__device__ __forceinline__ unsigned packbf2(float a, float b){
  return (unsigned)f2bf(a) | ((unsigned)f2bf(b) << 16);
}
__device__ __forceinline__ float unpacklo(unsigned p){
  union { unsigned u; float f; } v; v.u = p << 16; return v.f;
}
__device__ __forceinline__ float unpackhi(unsigned p){
  union { unsigned u; float f; } v; v.u = p & 0xffff0000u; return v.f;
}

// Pre-swizzle W_ih[:, :D] and W_hh into bf16 MFMA B-fragment order:
// frag value at (tn, tk, lane, j) = W[c = tn*16 + (lane&15)][d = tk*32 + (lane>>4)*8 + j]
// stored flat at ((tn*8+tk)*64 + lane)*8 + j.  FW1 first, FWhh second.
__global__ void prep_weights(const float* __restrict__ Wih,
                             const float* __restrict__ Whh,
                             unsigned short* __restrict__ fw){
  int id = blockIdx.x * 256 + threadIdx.x;     // 0 .. 2*FRAG_ELEMS-1
  int arr = (id >= FRAG_ELEMS);
  int r = arr ? (id - FRAG_ELEMS) : id;
  int j  = r & 7;
  int l  = (r >> 3) & 63;
  int tk = (r >> 9) & 7;
  int tn = r >> 12;                            // 0..47
  int c  = tn * 16 + (l & 15);                 // 0..767
  int d  = tk * 32 + ((l >> 4) << 3) + j;      // 0..255
  float v = arr ? Whh[c * 256 + d] : Wih[c * 512 + d];
  fw[id] = f2bf(v);
}

__global__ __launch_bounds__(NT, 4) void gru_main(
    const float* __restrict__ item, const float* __restrict__ user,
    const float* __restrict__ b_ih, const float* __restrict__ b_hh,
    const float* __restrict__ w_out, const float* __restrict__ b_out,
    const int* __restrict__ length, const unsigned short* __restrict__ ws,
    float* __restrict__ out)
{
  // A-fragment layout: elem (mt, tk, lane, j) at ((mt*8+tk)*64+lane)*8+j
  __shared__ unsigned short xs[2][2][2*8*64*8];  // [superstep-buf][step], 64 KB
  __shared__ unsigned short hfrag[2][2*8*64*8];  // ping-pong within superstep, 32 KB
  __shared__ float yp[3][16][2][4][4];           // 6 KB, triple-buffered
  __shared__ uint2 park[6*1024];                 // 48 KB: k1's gi, same-thread write/read

  const int tid  = threadIdx.x;
  const int lane = tid & 63;
  const int w    = tid >> 6;        // wave 0..15 == column group g
  const int col  = lane & 15;       // C-layout col
  const int q    = lane >> 4;       // quad
  const int nb   = blockIdx.x * ROWS;
  const int b    = nb / SS;         // one user per block

  const short8* fw1 = (const short8*)ws;
  const short8* fwh = fw1 + (FRAG_ELEMS/8);

  // per-column constants (this thread owns output channel d for 8 rows)
  const int d    = w*16 + col;
  const float br_  = b_ih[d]       + b_hh[d];
  const float bz_  = b_ih[256 + d] + b_hh[256 + d];
  const float bin_ = b_ih[512 + d];
  const float bhn_ = b_hh[512 + d];
  const float wo_  = w_out[d];

  // h0 = user_embs[b, clip(length[b]-1,0)]; identical for all 32 rows
  int idx = length[b] - 1; if (idx < 0) idx = 0;
  const float u0 = user[((size_t)b*SS + idx)*DD + d];
  float h[2][4];
  #pragma unroll
  for (int mt = 0; mt < 2; ++mt)
    #pragma unroll
    for (int reg = 0; reg < 4; ++reg)
      h[mt][reg] = u0;

  // write h0 into hfrag[0] (A-fragment layout), owner-thread scatter
  const int tkk = d >> 5;
  const int slb = ((d >> 3) & 3) * 16;
  const int dj  = d & 7;
  {
    unsigned short hb = f2bf(u0);
    #pragma unroll
    for (int mt = 0; mt < 2; ++mt)
      #pragma unroll
      for (int reg = 0; reg < 4; ++reg)
        hfrag[0][((mt*8 + tkk)*64 + slb + q*4 + reg)*8 + dj] = hb;
  }

  // cooperative x staging geometry: thread covers row = tid>>5, 8 d's at (tid&31)*8
  const int xrow = tid >> 5;        // 0..31
  const int xo   = tid & 31;        // which 8-wide d chunk
  const int xmt  = xrow >> 4;
  const int xtk  = xo >> 2;
  const int xsl  = (xo & 3)*16 + (xrow & 15);
  const int xdst = ((xmt*8 + xtk)*64 + xsl)*8;

  // prologue: stage x for steps 0 and 1 into xs[0][0], xs[0][1]
  #pragma unroll
  for (int s = 0; s < 2; ++s){
    const float4* p = (const float4*)(item + ((size_t)(nb + xrow)*KK + s)*DD + xo*8);
    float4 a0 = p[0], a1 = p[1];
    unsigned short t[8];
    t[0]=f2bf(a0.x); t[1]=f2bf(a0.y); t[2]=f2bf(a0.z); t[3]=f2bf(a0.w);
    t[4]=f2bf(a1.x); t[5]=f2bf(a1.y); t[6]=f2bf(a1.z); t[7]=f2bf(a1.w);
    *(short8*)&xs[0][s][xdst] = *(short8*)t;
  }
  __syncthreads();

  const float bout = b_out[0];

  for (int j = 0; j < NSUP; ++j){
    const int k0  = 2*j;
    const int k1  = 2*j + 1;
    const int cb  = j & 1;
    const int nbf = cb ^ 1;

    // ---------------- phase A: gi for both steps, one W1 pass ----------------
    {
      f32x4 g0[2][3];   // step k0: [mt][gate r,z,n]
      f32x4 g1[2][3];   // step k1
      #pragma unroll
      for (int mt = 0; mt < 2; ++mt)
        #pragma unroll
        for (int g = 0; g < 3; ++g){
          f32x4 z4 = {0.f,0.f,0.f,0.f};
          g0[mt][g] = z4; g1[mt][g] = z4;
        }

      #pragma unroll
      for (int tk = 0; tk < 8; ++tk){
        short8 w1r = fw1[((w     )*8 + tk)*64 + lane];
        short8 w1z = fw1[((16 + w)*8 + tk)*64 + lane];
        short8 w1n = fw1[((32 + w)*8 + tk)*64 + lane];
        short8 a00 = *(const short8*)&xs[cb][0][((0*8 + tk)*64 + lane)*8];
        short8 a01 = *(const short8*)&xs[cb][0][((1*8 + tk)*64 + lane)*8];
        short8 a10 = *(const short8*)&xs[cb][1][((0*8 + tk)*64 + lane)*8];
        short8 a11 = *(const short8*)&xs[cb][1][((1*8 + tk)*64 + lane)*8];
        g0[0][0] = __builtin_amdgcn_mfma_f32_16x16x32_bf16(a00, w1r, g0[0][0], 0, 0, 0);
        g0[1][0] = __builtin_amdgcn_mfma_f32_16x16x32_bf16(a01, w1r, g0[1][0], 0, 0, 0);
        g1[0][0] = __builtin_amdgcn_mfma_f32_16x16x32_bf16(a10, w1r, g1[0][0], 0, 0, 0);
        g1[1][0] = __builtin_amdgcn_mfma_f32_16x16x32_bf16(a11, w1r, g1[1][0], 0, 0, 0);
        g0[0][1] = __builtin_amdgcn_mfma_f32_16x16x32_bf16(a00, w1z, g0[0][1], 0, 0, 0);
        g0[1][1] = __builtin_amdgcn_mfma_f32_16x16x32_bf16(a01, w1z, g0[1][1], 0, 0, 0);
        g1[0][1] = __builtin_amdgcn_mfma_f32_16x16x32_bf16(a10, w1z, g1[0][1], 0, 0, 0);
        g1[1][1] = __builtin_amdgcn_mfma_f32_16x16x32_bf16(a11, w1z, g1[1][1], 0, 0, 0);
        g0[0][2] = __builtin_amdgcn_mfma_f32_16x16x32_bf16(a00, w1n, g0[0][2], 0, 0, 0);
        g0[1][2] = __builtin_amdgcn_mfma_f32_16x16x32_bf16(a01, w1n, g0[1][2], 0, 0, 0);
        g1[0][2] = __builtin_amdgcn_mfma_f32_16x16x32_bf16(a10, w1n, g1[0][2], 0, 0, 0);
        g1[1][2] = __builtin_amdgcn_mfma_f32_16x16x32_bf16(a11, w1n, g1[1][2], 0, 0, 0);
      }

      // park k1's gi into LDS (packed bf16, SoA, same thread writes & reads ->
      // no barrier needed; frees all cross-phase VGPRs — R5's spill fix)
      #pragma unroll
      for (int mt = 0; mt < 2; ++mt)
        #pragma unroll
        for (int g = 0; g < 3; ++g){
          uint2 pk;
          pk.x = packbf2(g1[mt][g][0], g1[mt][g][1]);
          pk.y = packbf2(g1[mt][g][2], g1[mt][g][3]);
          park[(mt*3 + g)*1024 + tid] = pk;
        }

      // ---------------- phase B: step k0 (gh, gates) ----------------
      f32x4 gh[2][3];
      #pragma unroll
      for (int mt = 0; mt < 2; ++mt)
        #pragma unroll
        for (int g = 0; g < 3; ++g){
          f32x4 z4 = {0.f,0.f,0.f,0.f};
          gh[mt][g] = z4;
        }
      #pragma unroll
      for (int tk = 0; tk < 8; ++tk){
        short8 whr = fwh[((w     )*8 + tk)*64 + lane];
        short8 whz = fwh[((16 + w)*8 + tk)*64 + lane];
        short8 whn = fwh[((32 + w)*8 + tk)*64 + lane];
        short8 ah0 = *(const short8*)&hfrag[0][((0*8 + tk)*64 + lane)*8];
        short8 ah1 = *(const short8*)&hfrag[0][((1*8 + tk)*64 + lane)*8];
        gh[0][0] = __builtin_amdgcn_mfma_f32_16x16x32_bf16(ah0, whr, gh[0][0], 0, 0, 0);
        gh[1][0] = __builtin_amdgcn_mfma_f32_16x16x32_bf16(ah1, whr, gh[1][0], 0, 0, 0);
        gh[0][1] = __builtin_amdgcn_mfma_f32_16x16x32_bf16(ah0, whz, gh[0][1], 0, 0, 0);
        gh[1][1] = __builtin_amdgcn_mfma_f32_16x16x32_bf16(ah1, whz, gh[1][1], 0, 0, 0);
        gh[0][2] = __builtin_amdgcn_mfma_f32_16x16x32_bf16(ah0, whn, gh[0][2], 0, 0, 0);
        gh[1][2] = __builtin_amdgcn_mfma_f32_16x16x32_bf16(ah1, whn, gh[1][2], 0, 0, 0);
      }

      // gates k0
      float ypl[2][4];
      #pragma unroll
      for (int mt = 0; mt < 2; ++mt)
        #pragma unroll
        for (int reg = 0; reg < 4; ++reg){
          float rp = g0[mt][0][reg] + gh[mt][0][reg] + br_;
          float zp = g0[mt][1][reg] + gh[mt][1][reg] + bz_;
          float r  = 1.f / (1.f + __expf(-rp));
          float z  = 1.f / (1.f + __expf(-zp));
          float np = g0[mt][2][reg] + bin_ + r*(gh[mt][2][reg] + bhn_);
          np = fminf(fmaxf(np, -30.f), 30.f);
          float e  = __expf(2.f*np);
          float n  = (e - 1.f) / (e + 1.f);
          float hv = (1.f - z)*n + z*h[mt][reg];
          h[mt][reg] = hv;
          ypl[mt][reg] = hv * wo_;
        }

      #pragma unroll
      for (int mt = 0; mt < 2; ++mt)
        #pragma unroll
        for (int reg = 0; reg < 4; ++reg){
          float p = ypl[mt][reg];
          p += __shfl_xor(p, 1);
          p += __shfl_xor(p, 2);
          p += __shfl_xor(p, 4);
          p += __shfl_xor(p, 8);
          if (col == 0) yp[k0 % 3][w][mt][q][reg] = p;
        }

      // h_{k0+1} -> hfrag[1]
      #pragma unroll
      for (int mt = 0; mt < 2; ++mt)
        #pragma unroll
        for (int reg = 0; reg < 4; ++reg)
          hfrag[1][((mt*8 + tkk)*64 + slb + q*4 + reg)*8 + dj] = f2bf(h[mt][reg]);

      // stage x_{k0+2} into xs[nbf][0] (load-convert-store; no long-lived regs)
      if (j < NSUP-1){
        const float4* p = (const float4*)(item + ((size_t)(nb + xrow)*KK + (k0+2))*DD + xo*8);
        float4 xb0 = p[0], xb1 = p[1];
        unsigned short t[8];
        t[0]=f2bf(xb0.x); t[1]=f2bf(xb0.y); t[2]=f2bf(xb0.z); t[3]=f2bf(xb0.w);
        t[4]=f2bf(xb1.x); t[5]=f2bf(xb1.y); t[6]=f2bf(xb1.z); t[7]=f2bf(xb1.w);
        *(short8*)&xs[nbf][0][xdst] = *(short8*)t;
      }

      // finalize y for step k0-1
      if (j > 0 && tid < 32){
        float s = bout;
        #pragma unroll
        for (int ww = 0; ww < 16; ++ww)
          s += yp[(k0-1) % 3][ww][tid >> 4][(tid >> 2) & 3][tid & 3];
        out[(size_t)(nb + tid)*KK + (k0-1)] = s;
      }
    }
    __syncthreads();   // mid barrier: h_{k0+1} visible

    // ---------------- phase C: step k1 (gh, gates) ----------------
    {
      f32x4 gh[2][3];
      #pragma unroll
      for (int mt = 0; mt < 2; ++mt)
        #pragma unroll
        for (int g = 0; g < 3; ++g){
          f32x4 z4 = {0.f,0.f,0.f,0.f};
          gh[mt][g] = z4;
        }
      #pragma unroll
      for (int tk = 0; tk < 8; ++tk){
        short8 whr = fwh[((w     )*8 + tk)*64 + lane];
        short8 whz = fwh[((16 + w)*8 + tk)*64 + lane];
        short8 whn = fwh[((32 + w)*8 + tk)*64 + lane];
        short8 ah0 = *(const short8*)&hfrag[1][((0*8 + tk)*64 + lane)*8];
        short8 ah1 = *(const short8*)&hfrag[1][((1*8 + tk)*64 + lane)*8];
        gh[0][0] = __builtin_amdgcn_mfma_f32_16x16x32_bf16(ah0, whr, gh[0][0], 0, 0, 0);
        gh[1][0] = __builtin_amdgcn_mfma_f32_16x16x32_bf16(ah1, whr, gh[1][0], 0, 0, 0);
        gh[0][1] = __builtin_amdgcn_mfma_f32_16x16x32_bf16(ah0, whz, gh[0][1], 0, 0, 0);
        gh[1][1] = __builtin_amdgcn_mfma_f32_16x16x32_bf16(ah1, whz, gh[1][1], 0, 0, 0);
        gh[0][2] = __builtin_amdgcn_mfma_f32_16x16x32_bf16(ah0, whn, gh[0][2], 0, 0, 0);
        gh[1][2] = __builtin_amdgcn_mfma_f32_16x16x32_bf16(ah1, whn, gh[1][2], 0, 0, 0);
      }

      // gates k1 (gi unparked from LDS, same-thread)
      float ypl[2][4];
      #pragma unroll
      for (int mt = 0; mt < 2; ++mt){
        uint2 pr = park[(mt*3 + 0)*1024 + tid];
        uint2 pz = park[(mt*3 + 1)*1024 + tid];
        uint2 pn = park[(mt*3 + 2)*1024 + tid];
        #pragma unroll
        for (int reg = 0; reg < 4; ++reg){
          unsigned ur = (reg < 2) ? pr.x : pr.y;
          unsigned uz = (reg < 2) ? pz.x : pz.y;
          unsigned un = (reg < 2) ? pn.x : pn.y;
          float gir = (reg & 1) ? unpackhi(ur) : unpacklo(ur);
          float giz = (reg & 1) ? unpackhi(uz) : unpacklo(uz);
          float gin = (reg & 1) ? unpackhi(un) : unpacklo(un);
          float rp = gir + gh[mt][0][reg] + br_;
          float zp = giz + gh[mt][1][reg] + bz_;
          float r  = 1.f / (1.f + __expf(-rp));
          float z  = 1.f / (1.f + __expf(-zp));
          float np = gin + bin_ + r*(gh[mt][2][reg] + bhn_);
          np = fminf(fmaxf(np, -30.f), 30.f);
          float e  = __expf(2.f*np);
          float n  = (e - 1.f) / (e + 1.f);
          float hv = (1.f - z)*n + z*h[mt][reg];
          h[mt][reg] = hv;
          ypl[mt][reg] = hv * wo_;
        }
      }

      #pragma unroll
      for (int mt = 0; mt < 2; ++mt)
        #pragma unroll
        for (int reg = 0; reg < 4; ++reg){
          float p = ypl[mt][reg];
          p += __shfl_xor(p, 1);
          p += __shfl_xor(p, 2);
          p += __shfl_xor(p, 4);
          p += __shfl_xor(p, 8);
          if (col == 0) yp[k1 % 3][w][mt][q][reg] = p;
        }

      // h_{k1+1} -> hfrag[0] (read of hfrag[0] finished before mid barrier)
      #pragma unroll
      for (int mt = 0; mt < 2; ++mt)
        #pragma unroll
        for (int reg = 0; reg < 4; ++reg)
          hfrag[0][((mt*8 + tkk)*64 + slb + q*4 + reg)*8 + dj] = f2bf(h[mt][reg]);

      // stage x_{k1+2} into xs[nbf][1]
      if (j < NSUP-1){
        const float4* p = (const float4*)(item + ((size_t)(nb + xrow)*KK + (k1+2))*DD + xo*8);
        float4 xb0 = p[0], xb1 = p[1];
        unsigned short t[8];
        t[0]=f2bf(xb0.x); t[1]=f2bf(xb0.y); t[2]=f2bf(xb0.z); t[3]=f2bf(xb0.w);
        t[4]=f2bf(xb1.x); t[5]=f2bf(xb1.y); t[6]=f2bf(xb1.z); t[7]=f2bf(xb1.w);
        *(short8*)&xs[nbf][1][xdst] = *(short8*)t;
      }

      // finalize y for step k0 (yp[k0%3] written before mid barrier)
      if (tid < 32){
        float s = bout;
        #pragma unroll
        for (int ww = 0; ww < 16; ++ww)
          s += yp[k0 % 3][ww][tid >> 4][(tid >> 2) & 3][tid & 3];
        out[(size_t)(nb + tid)*KK + k0] = s;
      }
    }
    __syncthreads();   // end barrier: h_{k1+1}, staged x visible
  }

  // finalize y for the last step
  if (tid < 32){
    float s = bout;
    #pragma unroll
    for (int ww = 0; ww < 16; ++ww)
      s += yp[(KK-1) % 3][ww][tid >> 4][(tid >> 2) & 3][tid & 3];
    out[(size_t)(nb + tid)*KK + (KK-1)] = s;
  }
}

extern "C" void kernel_launch(void* const* d_in, const int* in_sizes, int n_in,
                              void* d_out, int out_size, void* d_ws, size_t ws_size,
                              hipStream_t stream) {
  const float* item   = (const float*)d_in[0];
  const float* user   = (const float*)d_in[1];
  const float* W_ih   = (const float*)d_in[2];
  const float* W_hh   = (const float*)d_in[3];
  const float* b_ih   = (const float*)d_in[4];
  const float* b_hh   = (const float*)d_in[5];
  const float* w_out  = (const float*)d_in[6];
  const float* b_out  = (const float*)d_in[7];
  const int*   length = (const int*)d_in[8];
  unsigned short* ws  = (unsigned short*)d_ws;   // needs 768 KB
  float* out = (float*)d_out;

  hipLaunchKernelGGL(prep_weights, dim3((2*FRAG_ELEMS)/256), dim3(256), 0, stream,
                     W_ih, W_hh, ws);
  hipLaunchKernelGGL(gru_main, dim3(NBLK), dim3(NT), 0, stream,
                     item, user, b_ih, b_hh, w_out, b_out, length, ws, out);
}

// Round 7
// 394.961 us; speedup vs baseline: 1.3079x; 1.0708x over previous
//
#include <hip/hip_runtime.h>

#define BB 128
#define SS 64
#define KK 10
#define DD 256
#define NN (BB*SS)        // 8192 rows
#define ROWS 32           // rows per block
#define NBLK (NN/ROWS)    // 256 blocks = 1 per CU
#define NT 1024           // 16 waves -> 4 waves/SIMD (128 regs/thread: 64 arch + 64 acc)

typedef __attribute__((ext_vector_type(8))) short short8;
typedef __attribute__((ext_vector_type(4))) float f32x4;

#define FRAG_ELEMS (48*8*64*8)   // 196608 bf16 values per weight matrix
#define WS_WBYTES  (2u*FRAG_ELEMS*2u)          // 786432 B: fw1 + fwh
#define GI_BYTES   (256ull*KK*6*1024*8)        // 125829120 B
#define WS_NEED    ((size_t)WS_WBYTES + (size_t)GI_BYTES)

__device__ __forceinline__ unsigned short f2bf(float f){
  union { float f; unsigned u; } v; v.f = f;
  unsigned r = (v.u + 0x7FFFu + ((v.u >> 16) & 1u)) >> 16;
  return (unsigned short)r;
}
__device__ __forceinline__ unsigned packbf2(float a, float b){
  return (unsigned)f2bf(a) | ((unsigned)f2bf(b) << 16);
}
__device__ __forceinline__ float unpacklo(unsigned p){
  union { unsigned u; float f; } v; v.u = p << 16; return v.f;
}
__device__ __forceinline__ float unpackhi(unsigned p){
  union { unsigned u; float f; } v; v.u = p & 0xffff0000u; return v.f;
}

// Pre-swizzle W_ih[:, :D] and W_hh into bf16 MFMA B-fragment order:
// frag value at (tn, tk, lane, j) = W[c = tn*16 + (lane&15)][d = tk*32 + (lane>>4)*8 + j]
// stored flat at ((tn*8+tk)*64 + lane)*8 + j.  FW1 first, FWhh second.
__global__ void prep_weights(const float* __restrict__ Wih,
                             const float* __restrict__ Whh,
                             unsigned short* __restrict__ fw){
  int id = blockIdx.x * 256 + threadIdx.x;     // 0 .. 2*FRAG_ELEMS-1
  int arr = (id >= FRAG_ELEMS);
  int r = arr ? (id - FRAG_ELEMS) : id;
  int j  = r & 7;
  int l  = (r >> 3) & 63;
  int tk = (r >> 9) & 7;
  int tn = r >> 12;                            // 0..47
  int c  = tn * 16 + (l & 15);                 // 0..767
  int d  = tk * 32 + ((l >> 4) << 3) + j;      // 0..255
  float v = arr ? Whh[c * 256 + d] : Wih[c * 512 + d];
  fw[id] = f2bf(v);
}

// ---------------------------------------------------------------------------
// Kernel 2: gi = x @ W1^T for ALL 10 steps. 2-step chunks so W1 fragments are
// read once per 2 steps. Only long-lived state: 48 accumulator regs. Results
// stored packed-bf16, same-thread layout consumed by gru_rec.
// ---------------------------------------------------------------------------
__global__ __launch_bounds__(NT, 4) void gi_gemm(
    const float* __restrict__ item, const unsigned short* __restrict__ ws,
    uint2* __restrict__ gi)
{
  __shared__ unsigned short xs[2][2][2*8*64*8];   // [chunk-buf][step], 64 KB

  const int tid  = threadIdx.x;
  const int lane = tid & 63;
  const int w    = tid >> 6;        // wave = column group g; channels d, 256+d, 512+d
  const int nb   = blockIdx.x * ROWS;

  const short8* fw1 = (const short8*)ws;

  const int xrow = tid >> 5;        // 0..31
  const int xo   = tid & 31;
  const int xmt  = xrow >> 4;
  const int xtk  = xo >> 2;
  const int xsl  = (xo & 3)*16 + (xrow & 15);
  const int xdst = ((xmt*8 + xtk)*64 + xsl)*8;

  // stage chunk 0 (k=0,1)
  #pragma unroll
  for (int s = 0; s < 2; ++s){
    const float4* p = (const float4*)(item + ((size_t)(nb + xrow)*KK + s)*DD + xo*8);
    float4 a0 = p[0], a1 = p[1];
    unsigned short t[8];
    t[0]=f2bf(a0.x); t[1]=f2bf(a0.y); t[2]=f2bf(a0.z); t[3]=f2bf(a0.w);
    t[4]=f2bf(a1.x); t[5]=f2bf(a1.y); t[6]=f2bf(a1.z); t[7]=f2bf(a1.w);
    *(short8*)&xs[0][s][xdst] = *(short8*)t;
  }
  __syncthreads();

  for (int j = 0; j < KK/2; ++j){
    const int cb  = j & 1;
    const int nbf = cb ^ 1;

    f32x4 ga[2][2][3];   // [step][mt][gate r,z,n]
    #pragma unroll
    for (int s = 0; s < 2; ++s)
      #pragma unroll
      for (int mt = 0; mt < 2; ++mt)
        #pragma unroll
        for (int gg = 0; gg < 3; ++gg){
          f32x4 z4 = {0.f,0.f,0.f,0.f};
          ga[s][mt][gg] = z4;
        }

    #pragma unroll
    for (int tk = 0; tk < 8; ++tk){
      short8 w1r = fw1[((w     )*8 + tk)*64 + lane];
      short8 w1z = fw1[((16 + w)*8 + tk)*64 + lane];
      short8 w1n = fw1[((32 + w)*8 + tk)*64 + lane];
      short8 a00 = *(const short8*)&xs[cb][0][((0*8 + tk)*64 + lane)*8];
      short8 a01 = *(const short8*)&xs[cb][0][((1*8 + tk)*64 + lane)*8];
      short8 a10 = *(const short8*)&xs[cb][1][((0*8 + tk)*64 + lane)*8];
      short8 a11 = *(const short8*)&xs[cb][1][((1*8 + tk)*64 + lane)*8];
      ga[0][0][0] = __builtin_amdgcn_mfma_f32_16x16x32_bf16(a00, w1r, ga[0][0][0], 0, 0, 0);
      ga[0][1][0] = __builtin_amdgcn_mfma_f32_16x16x32_bf16(a01, w1r, ga[0][1][0], 0, 0, 0);
      ga[1][0][0] = __builtin_amdgcn_mfma_f32_16x16x32_bf16(a10, w1r, ga[1][0][0], 0, 0, 0);
      ga[1][1][0] = __builtin_amdgcn_mfma_f32_16x16x32_bf16(a11, w1r, ga[1][1][0], 0, 0, 0);
      ga[0][0][1] = __builtin_amdgcn_mfma_f32_16x16x32_bf16(a00, w1z, ga[0][0][1], 0, 0, 0);
      ga[0][1][1] = __builtin_amdgcn_mfma_f32_16x16x32_bf16(a01, w1z, ga[0][1][1], 0, 0, 0);
      ga[1][0][1] = __builtin_amdgcn_mfma_f32_16x16x32_bf16(a10, w1z, ga[1][0][1], 0, 0, 0);
      ga[1][1][1] = __builtin_amdgcn_mfma_f32_16x16x32_bf16(a11, w1z, ga[1][1][1], 0, 0, 0);
      ga[0][0][2] = __builtin_amdgcn_mfma_f32_16x16x32_bf16(a00, w1n, ga[0][0][2], 0, 0, 0);
      ga[0][1][2] = __builtin_amdgcn_mfma_f32_16x16x32_bf16(a01, w1n, ga[0][1][2], 0, 0, 0);
      ga[1][0][2] = __builtin_amdgcn_mfma_f32_16x16x32_bf16(a10, w1n, ga[1][0][2], 0, 0, 0);
      ga[1][1][2] = __builtin_amdgcn_mfma_f32_16x16x32_bf16(a11, w1n, ga[1][1][2], 0, 0, 0);
    }

    // stage next chunk into the other buffer (overlaps with pack/store)
    if (j < KK/2 - 1){
      #pragma unroll
      for (int s = 0; s < 2; ++s){
        const float4* p = (const float4*)(item + ((size_t)(nb + xrow)*KK + (2*j + 2 + s))*DD + xo*8);
        float4 a0 = p[0], a1 = p[1];
        unsigned short t[8];
        t[0]=f2bf(a0.x); t[1]=f2bf(a0.y); t[2]=f2bf(a0.z); t[3]=f2bf(a0.w);
        t[4]=f2bf(a1.x); t[5]=f2bf(a1.y); t[6]=f2bf(a1.z); t[7]=f2bf(a1.w);
        *(short8*)&xs[nbf][s][xdst] = *(short8*)t;
      }
    }

    // pack + store gi (packed bf16, SoA over tid for coalescing)
    #pragma unroll
    for (int s = 0; s < 2; ++s)
      #pragma unroll
      for (int mt = 0; mt < 2; ++mt)
        #pragma unroll
        for (int gg = 0; gg < 3; ++gg){
          uint2 pk;
          pk.x = packbf2(ga[s][mt][gg][0], ga[s][mt][gg][1]);
          pk.y = packbf2(ga[s][mt][gg][2], ga[s][mt][gg][3]);
          gi[(((size_t)blockIdx.x*KK + (2*j + s))*6 + (mt*3 + gg))*1024 + tid] = pk;
        }

    __syncthreads();
  }
}

// ---------------------------------------------------------------------------
// Kernel 3: recurrence only. Per step: gh = h @ Whh^T (384 KB/CU weight
// stream — half of R3), gi loaded pre-computed (48 B/thread), gates, y.
// ---------------------------------------------------------------------------
__global__ __launch_bounds__(NT, 4) void gru_rec(
    const float* __restrict__ user,
    const float* __restrict__ b_ih, const float* __restrict__ b_hh,
    const float* __restrict__ w_out, const float* __restrict__ b_out,
    const int* __restrict__ length, const unsigned short* __restrict__ ws,
    const uint2* __restrict__ gi, float* __restrict__ out)
{
  __shared__ unsigned short hfrag[2][2*8*64*8];  // ping-pong, 32 KB
  __shared__ float yp[3][16][2][4][4];           // 6 KB, triple-buffered

  const int tid  = threadIdx.x;
  const int lane = tid & 63;
  const int w    = tid >> 6;
  const int col  = lane & 15;
  const int q    = lane >> 4;
  const int nb   = blockIdx.x * ROWS;
  const int b    = nb / SS;

  const short8* fwh = (const short8*)ws + (FRAG_ELEMS/8);

  const int d    = w*16 + col;
  const float br_  = b_ih[d]       + b_hh[d];
  const float bz_  = b_ih[256 + d] + b_hh[256 + d];
  const float bin_ = b_ih[512 + d];
  const float bhn_ = b_hh[512 + d];
  const float wo_  = w_out[d];

  int idx = length[b] - 1; if (idx < 0) idx = 0;
  const float u0 = user[((size_t)b*SS + idx)*DD + d];
  float h[2][4];
  #pragma unroll
  for (int mt = 0; mt < 2; ++mt)
    #pragma unroll
    for (int reg = 0; reg < 4; ++reg)
      h[mt][reg] = u0;

  const int tkk = d >> 5;
  const int slb = ((d >> 3) & 3) * 16;
  const int dj  = d & 7;
  {
    unsigned short hb = f2bf(u0);
    #pragma unroll
    for (int mt = 0; mt < 2; ++mt)
      #pragma unroll
      for (int reg = 0; reg < 4; ++reg)
        hfrag[0][((mt*8 + tkk)*64 + slb + q*4 + reg)*8 + dj] = hb;
  }
  __syncthreads();

  const float bout = b_out[0];

  for (int k = 0; k < KK; ++k){
    const int cb  = k & 1;
    const int nbf = cb ^ 1;

    // load this step's precomputed gi (issued early; consumed in gates)
    uint2 pg[6];
    #pragma unroll
    for (int c = 0; c < 6; ++c)
      pg[c] = gi[(((size_t)blockIdx.x*KK + k)*6 + c)*1024 + tid];

    f32x4 gh[2][3];
    #pragma unroll
    for (int mt = 0; mt < 2; ++mt)
      #pragma unroll
      for (int gg = 0; gg < 3; ++gg){
        f32x4 z4 = {0.f,0.f,0.f,0.f};
        gh[mt][gg] = z4;
      }
    #pragma unroll
    for (int tk = 0; tk < 8; ++tk){
      short8 whr = fwh[((w     )*8 + tk)*64 + lane];
      short8 whz = fwh[((16 + w)*8 + tk)*64 + lane];
      short8 whn = fwh[((32 + w)*8 + tk)*64 + lane];
      short8 ah0 = *(const short8*)&hfrag[cb][((0*8 + tk)*64 + lane)*8];
      short8 ah1 = *(const short8*)&hfrag[cb][((1*8 + tk)*64 + lane)*8];
      gh[0][0] = __builtin_amdgcn_mfma_f32_16x16x32_bf16(ah0, whr, gh[0][0], 0, 0, 0);
      gh[1][0] = __builtin_amdgcn_mfma_f32_16x16x32_bf16(ah1, whr, gh[1][0], 0, 0, 0);
      gh[0][1] = __builtin_amdgcn_mfma_f32_16x16x32_bf16(ah0, whz, gh[0][1], 0, 0, 0);
      gh[1][1] = __builtin_amdgcn_mfma_f32_16x16x32_bf16(ah1, whz, gh[1][1], 0, 0, 0);
      gh[0][2] = __builtin_amdgcn_mfma_f32_16x16x32_bf16(ah0, whn, gh[0][2], 0, 0, 0);
      gh[1][2] = __builtin_amdgcn_mfma_f32_16x16x32_bf16(ah1, whn, gh[1][2], 0, 0, 0);
    }

    // gates (gi unpacked from packed bf16, same-thread layout)
    float ypl[2][4];
    #pragma unroll
    for (int mt = 0; mt < 2; ++mt){
      uint2 pr = pg[mt*3 + 0];
      uint2 pz = pg[mt*3 + 1];
      uint2 pn = pg[mt*3 + 2];
      #pragma unroll
      for (int reg = 0; reg < 4; ++reg){
        unsigned ur = (reg < 2) ? pr.x : pr.y;
        unsigned uz = (reg < 2) ? pz.x : pz.y;
        unsigned un = (reg < 2) ? pn.x : pn.y;
        float gir = (reg & 1) ? unpackhi(ur) : unpacklo(ur);
        float giz = (reg & 1) ? unpackhi(uz) : unpacklo(uz);
        float gin = (reg & 1) ? unpackhi(un) : unpacklo(un);
        float rp = gir + gh[mt][0][reg] + br_;
        float zp = giz + gh[mt][1][reg] + bz_;
        float r  = 1.f / (1.f + __expf(-rp));
        float z  = 1.f / (1.f + __expf(-zp));
        float np = gin + bin_ + r*(gh[mt][2][reg] + bhn_);
        np = fminf(fmaxf(np, -30.f), 30.f);
        float e  = __expf(2.f*np);
        float n  = (e - 1.f) / (e + 1.f);
        float hv = (1.f - z)*n + z*h[mt][reg];
        h[mt][reg] = hv;
        ypl[mt][reg] = hv * wo_;
      }
    }

    #pragma unroll
    for (int mt = 0; mt < 2; ++mt)
      #pragma unroll
      for (int reg = 0; reg < 4; ++reg){
        float p = ypl[mt][reg];
        p += __shfl_xor(p, 1);
        p += __shfl_xor(p, 2);
        p += __shfl_xor(p, 4);
        p += __shfl_xor(p, 8);
        if (col == 0) yp[k % 3][w][mt][q][reg] = p;
      }

    // h' -> hfrag[nbf]
    #pragma unroll
    for (int mt = 0; mt < 2; ++mt)
      #pragma unroll
      for (int reg = 0; reg < 4; ++reg)
        hfrag[nbf][((mt*8 + tkk)*64 + slb + q*4 + reg)*8 + dj] = f2bf(h[mt][reg]);

    // finalize y for step k-1
    if (k > 0 && tid < 32){
      float s = bout;
      #pragma unroll
      for (int ww = 0; ww < 16; ++ww)
        s += yp[(k-1) % 3][ww][tid >> 4][(tid >> 2) & 3][tid & 3];
      out[(size_t)(nb + tid)*KK + (k-1)] = s;
    }

    __syncthreads();
  }

  if (tid < 32){
    float s = bout;
    #pragma unroll
    for (int ww = 0; ww < 16; ++ww)
      s += yp[(KK-1) % 3][ww][tid >> 4][(tid >> 2) & 3][tid & 3];
    out[(size_t)(nb + tid)*KK + (KK-1)] = s;
  }
}

// ---------------------------------------------------------------------------
// Fallback: R3's verified single recurrent kernel (136 µs, no spill) in case
// ws_size can't hold the gi buffer.
// ---------------------------------------------------------------------------
__global__ __launch_bounds__(NT, 4) void gru_fb(
    const float* __restrict__ item, const float* __restrict__ user,
    const float* __restrict__ b_ih, const float* __restrict__ b_hh,
    const float* __restrict__ w_out, const float* __restrict__ b_out,
    const int* __restrict__ length, const unsigned short* __restrict__ ws,
    float* __restrict__ out)
{
  __shared__ unsigned short xfrag[2][2*8*64*8];
  __shared__ unsigned short hfrag[2][2*8*64*8];
  __shared__ float yp[3][16][2][4][4];

  const int tid  = threadIdx.x;
  const int lane = tid & 63;
  const int w    = tid >> 6;
  const int col  = lane & 15;
  const int q    = lane >> 4;
  const int nb   = blockIdx.x * ROWS;
  const int b    = nb / SS;

  const short8* fw1 = (const short8*)ws;
  const short8* fwh = fw1 + (FRAG_ELEMS/8);

  const int d    = w*16 + col;
  const float br_  = b_ih[d]       + b_hh[d];
  const float bz_  = b_ih[256 + d] + b_hh[256 + d];
  const float bin_ = b_ih[512 + d];
  const float bhn_ = b_hh[512 + d];
  const float wo_  = w_out[d];

  int idx = length[b] - 1; if (idx < 0) idx = 0;
  const float u0 = user[((size_t)b*SS + idx)*DD + d];
  float h[2][4];
  #pragma unroll
  for (int mt = 0; mt < 2; ++mt)
    #pragma unroll
    for (int reg = 0; reg < 4; ++reg)
      h[mt][reg] = u0;

  const int tkk = d >> 5;
  const int slb = ((d >> 3) & 3) * 16;
  const int dj  = d & 7;
  {
    unsigned short hb = f2bf(u0);
    #pragma unroll
    for (int mt = 0; mt < 2; ++mt)
      #pragma unroll
      for (int reg = 0; reg < 4; ++reg)
        hfrag[0][((mt*8 + tkk)*64 + slb + q*4 + reg)*8 + dj] = hb;
  }

  const int xrow = tid >> 5;
  const int xo   = tid & 31;
  const int xmt  = xrow >> 4;
  const int xtk  = xo >> 2;
  const int xsl  = (xo & 3)*16 + (xrow & 15);
  {
    const float4* p = (const float4*)(item + ((size_t)(nb + xrow)*KK + 0)*DD + xo*8);
    float4 a0 = p[0], a1 = p[1];
    unsigned short t[8];
    t[0]=f2bf(a0.x); t[1]=f2bf(a0.y); t[2]=f2bf(a0.z); t[3]=f2bf(a0.w);
    t[4]=f2bf(a1.x); t[5]=f2bf(a1.y); t[6]=f2bf(a1.z); t[7]=f2bf(a1.w);
    *(short8*)&xfrag[0][((xmt*8 + xtk)*64 + xsl)*8] = *(short8*)t;
  }
  __syncthreads();

  const float bout = b_out[0];

  for (int k = 0; k < KK; ++k){
    const int cb  = k & 1;
    const int nbf = cb ^ 1;

    f32x4 acc[2][4];
    #pragma unroll
    for (int mt = 0; mt < 2; ++mt)
      #pragma unroll
      for (int kd = 0; kd < 4; ++kd){
        f32x4 z4 = {0.f, 0.f, 0.f, 0.f};
        acc[mt][kd] = z4;
      }

    #pragma unroll 2
    for (int tk = 0; tk < 8; ++tk){
      short8 ax0 = *(const short8*)&xfrag[cb][((0*8 + tk)*64 + lane)*8];
      short8 ax1 = *(const short8*)&xfrag[cb][((1*8 + tk)*64 + lane)*8];
      short8 ah0 = *(const short8*)&hfrag[cb][((0*8 + tk)*64 + lane)*8];
      short8 ah1 = *(const short8*)&hfrag[cb][((1*8 + tk)*64 + lane)*8];
      short8 w1r = fw1[((w     )*8 + tk)*64 + lane];
      short8 w1z = fw1[((16 + w)*8 + tk)*64 + lane];
      short8 w1n = fw1[((32 + w)*8 + tk)*64 + lane];
      short8 whr = fwh[((w     )*8 + tk)*64 + lane];
      short8 whz = fwh[((16 + w)*8 + tk)*64 + lane];
      short8 whn = fwh[((32 + w)*8 + tk)*64 + lane];
      acc[0][0] = __builtin_amdgcn_mfma_f32_16x16x32_bf16(ax0, w1r, acc[0][0], 0, 0, 0);
      acc[0][0] = __builtin_amdgcn_mfma_f32_16x16x32_bf16(ah0, whr, acc[0][0], 0, 0, 0);
      acc[0][1] = __builtin_amdgcn_mfma_f32_16x16x32_bf16(ax0, w1z, acc[0][1], 0, 0, 0);
      acc[0][1] = __builtin_amdgcn_mfma_f32_16x16x32_bf16(ah0, whz, acc[0][1], 0, 0, 0);
      acc[0][2] = __builtin_amdgcn_mfma_f32_16x16x32_bf16(ax0, w1n, acc[0][2], 0, 0, 0);
      acc[0][3] = __builtin_amdgcn_mfma_f32_16x16x32_bf16(ah0, whn, acc[0][3], 0, 0, 0);
      acc[1][0] = __builtin_amdgcn_mfma_f32_16x16x32_bf16(ax1, w1r, acc[1][0], 0, 0, 0);
      acc[1][0] = __builtin_amdgcn_mfma_f32_16x16x32_bf16(ah1, whr, acc[1][0], 0, 0, 0);
      acc[1][1] = __builtin_amdgcn_mfma_f32_16x16x32_bf16(ax1, w1z, acc[1][1], 0, 0, 0);
      acc[1][1] = __builtin_amdgcn_mfma_f32_16x16x32_bf16(ah1, whz, acc[1][1], 0, 0, 0);
      acc[1][2] = __builtin_amdgcn_mfma_f32_16x16x32_bf16(ax1, w1n, acc[1][2], 0, 0, 0);
      acc[1][3] = __builtin_amdgcn_mfma_f32_16x16x32_bf16(ah1, whn, acc[1][3], 0, 0, 0);
    }

    float4 xn0, xn1;
    if (k < KK-1){
      const float4* p = (const float4*)(item + ((size_t)(nb + xrow)*KK + (k+1))*DD + xo*8);
      xn0 = p[0]; xn1 = p[1];
    }

    float ypl[2][4];
    #pragma unroll
    for (int mt = 0; mt < 2; ++mt)
      #pragma unroll
      for (int reg = 0; reg < 4; ++reg){
        float rp = acc[mt][0][reg] + br_;
        float zp = acc[mt][1][reg] + bz_;
        float r  = 1.f / (1.f + __expf(-rp));
        float z  = 1.f / (1.f + __expf(-zp));
        float np = acc[mt][2][reg] + bin_ + r*(acc[mt][3][reg] + bhn_);
        np = fminf(fmaxf(np, -30.f), 30.f);
        float e  = __expf(2.f*np);
        float n  = (e - 1.f) / (e + 1.f);
        float hv = (1.f - z)*n + z*h[mt][reg];
        h[mt][reg] = hv;
        ypl[mt][reg] = hv * wo_;
      }

    #pragma unroll
    for (int mt = 0; mt < 2; ++mt)
      #pragma unroll
      for (int reg = 0; reg < 4; ++reg){
        float p = ypl[mt][reg];
        p += __shfl_xor(p, 1);
        p += __shfl_xor(p, 2);
        p += __shfl_xor(p, 4);
        p += __shfl_xor(p, 8);
        if (col == 0) yp[k % 3][w][mt][q][reg] = p;
      }

    #pragma unroll
    for (int mt = 0; mt < 2; ++mt)
      #pragma unroll
      for (int reg = 0; reg < 4; ++reg)
        hfrag[nbf][((mt*8 + tkk)*64 + slb + q*4 + reg)*8 + dj] = f2bf(h[mt][reg]);

    if (k < KK-1){
      unsigned short t[8];
      t[0]=f2bf(xn0.x); t[1]=f2bf(xn0.y); t[2]=f2bf(xn0.z); t[3]=f2bf(xn0.w);
      t[4]=f2bf(xn1.x); t[5]=f2bf(xn1.y); t[6]=f2bf(xn1.z); t[7]=f2bf(xn1.w);
      *(short8*)&xfrag[nbf][((xmt*8 + xtk)*64 + xsl)*8] = *(short8*)t;
    }

    if (k > 0 && tid < 32){
      float s = bout;
      #pragma unroll
      for (int ww = 0; ww < 16; ++ww)
        s += yp[(k-1) % 3][ww][tid >> 4][(tid >> 2) & 3][tid & 3];
      out[(size_t)(nb + tid)*KK + (k-1)] = s;
    }

    __syncthreads();
  }

  if (tid < 32){
    float s = bout;
    #pragma unroll
    for (int ww = 0; ww < 16; ++ww)
      s += yp[(KK-1) % 3][ww][tid >> 4][(tid >> 2) & 3][tid & 3];
    out[(size_t)(nb + tid)*KK + (KK-1)] = s;
  }
}

extern "C" void kernel_launch(void* const* d_in, const int* in_sizes, int n_in,
                              void* d_out, int out_size, void* d_ws, size_t ws_size,
                              hipStream_t stream) {
  const float* item   = (const float*)d_in[0];
  const float* user   = (const float*)d_in[1];
  const float* W_ih   = (const float*)d_in[2];
  const float* W_hh   = (const float*)d_in[3];
  const float* b_ih   = (const float*)d_in[4];
  const float* b_hh   = (const float*)d_in[5];
  const float* w_out  = (const float*)d_in[6];
  const float* b_out  = (const float*)d_in[7];
  const int*   length = (const int*)d_in[8];
  unsigned short* ws  = (unsigned short*)d_ws;
  float* out = (float*)d_out;

  hipLaunchKernelGGL(prep_weights, dim3((2*FRAG_ELEMS)/256), dim3(256), 0, stream,
                     W_ih, W_hh, ws);

  if (ws_size >= WS_NEED){
    uint2* gi = (uint2*)((char*)d_ws + WS_WBYTES);
    hipLaunchKernelGGL(gi_gemm, dim3(NBLK), dim3(NT), 0, stream, item, ws, gi);
    hipLaunchKernelGGL(gru_rec, dim3(NBLK), dim3(NT), 0, stream,
                       user, b_ih, b_hh, w_out, b_out, length, ws, gi, out);
  } else {
    hipLaunchKernelGGL(gru_fb, dim3(NBLK), dim3(NT), 0, stream,
                       item, user, b_ih, b_hh, w_out, b_out, length, ws, out);
  }
}

// Round 8
// 313.981 us; speedup vs baseline: 1.6453x; 1.2579x over previous
//
#include <hip/hip_runtime.h>

#define BB 128
#define SS 64
#define KK 10
#define DD 256
#define NN (BB*SS)        // 8192 rows
#define ROWS 32           // rows per block
#define NBLK (NN/ROWS)    // 256 blocks = 1 per CU

typedef __attribute__((ext_vector_type(8))) short short8;
typedef __attribute__((ext_vector_type(4))) float f32x4;

#define FRAG_ELEMS (48*8*64*8)   // 196608 bf16 values per weight matrix
#define WS_WBYTES  (2u*FRAG_ELEMS*2u)          // 786432 B: fw1 + fwh
#define GI_STEP_BYTES 49152                     // 6 comps * 1024 slots * 8 B
#define GI_BYTES   ((size_t)NBLK*KK*GI_STEP_BYTES)   // 125829120 B
#define WS_NEED    ((size_t)WS_WBYTES + GI_BYTES)

__device__ __forceinline__ unsigned short f2bf(float f){
  union { float f; unsigned u; } v; v.f = f;
  unsigned r = (v.u + 0x7FFFu + ((v.u >> 16) & 1u)) >> 16;
  return (unsigned short)r;
}
__device__ __forceinline__ unsigned packbf2(float a, float b){
  return (unsigned)f2bf(a) | ((unsigned)f2bf(b) << 16);
}
__device__ __forceinline__ float unpacklo(unsigned p){
  union { unsigned u; float f; } v; v.u = p << 16; return v.f;
}
__device__ __forceinline__ float unpackhi(unsigned p){
  union { unsigned u; float f; } v; v.u = p & 0xffff0000u; return v.f;
}

// Pre-swizzle W_ih[:, :D] and W_hh into bf16 MFMA B-fragment order:
// frag value at (tn, tk, lane, j) = W[c = tn*16 + (lane&15)][d = tk*32 + (lane>>4)*8 + j]
// stored flat at ((tn*8+tk)*64 + lane)*8 + j.  FW1 first, FWhh second.
__global__ void prep_weights(const float* __restrict__ Wih,
                             const float* __restrict__ Whh,
                             unsigned short* __restrict__ fw){
  int id = blockIdx.x * 256 + threadIdx.x;     // 0 .. 2*FRAG_ELEMS-1
  int arr = (id >= FRAG_ELEMS);
  int r = arr ? (id - FRAG_ELEMS) : id;
  int j  = r & 7;
  int l  = (r >> 3) & 63;
  int tk = (r >> 9) & 7;
  int tn = r >> 12;                            // 0..47
  int c  = tn * 16 + (l & 15);                 // 0..767
  int d  = tk * 32 + ((l >> 4) << 3) + j;      // 0..255
  float v = arr ? Whh[c * 256 + d] : Wih[c * 512 + d];
  fw[id] = f2bf(v);
}

// ---------------------------------------------------------------------------
// Kernel 2 (v2): gi = x @ W1^T for all 10 steps. 512 threads / 8 waves at
// 2 waves/SIMD (256 regs). Each wave holds W1 fragments for its 2 column
// groups in 192 registers for the WHOLE kernel — W1 read once per block.
// Accumulator footprint kept to 12 regs by looping (mt, group) serially.
// ---------------------------------------------------------------------------
__global__ __launch_bounds__(512, 2) void gi_gemm(
    const float* __restrict__ item, const unsigned short* __restrict__ ws,
    uint2* __restrict__ gi)
{
  __shared__ unsigned short xs[2][2*8*64*8];   // double-buffered x tile, 32 KB

  const int tid  = threadIdx.x;
  const int lane = tid & 63;
  const int w    = tid >> 6;        // wave 0..7 -> groups 2w, 2w+1
  const int nb   = blockIdx.x * ROWS;

  const short8* fw1 = (const short8*)ws;

  // W1 fragments resident in registers: [group][gate][tk]
  short8 W[2][3][8];
  #pragma unroll
  for (int gg = 0; gg < 2; ++gg)
    #pragma unroll
    for (int gate = 0; gate < 3; ++gate)
      #pragma unroll
      for (int tk = 0; tk < 8; ++tk)
        W[gg][gate][tk] = fw1[(((gate*16) + (2*w + gg))*8 + tk)*64 + lane];

  // x staging: thread covers row = tid>>4, 16 d's at (tid&15)*16
  const int xrow = tid >> 4;        // 0..31
  const int xq   = tid & 15;
  {
    const float4* p = (const float4*)(item + ((size_t)(nb + xrow)*KK + 0)*DD + xq*16);
    float4 a0 = p[0], a1 = p[1], a2 = p[2], a3 = p[3];
    unsigned short t[16];
    t[0]=f2bf(a0.x); t[1]=f2bf(a0.y); t[2]=f2bf(a0.z); t[3]=f2bf(a0.w);
    t[4]=f2bf(a1.x); t[5]=f2bf(a1.y); t[6]=f2bf(a1.z); t[7]=f2bf(a1.w);
    t[8]=f2bf(a2.x); t[9]=f2bf(a2.y); t[10]=f2bf(a2.z); t[11]=f2bf(a2.w);
    t[12]=f2bf(a3.x); t[13]=f2bf(a3.y); t[14]=f2bf(a3.z); t[15]=f2bf(a3.w);
    int m = xrow & 15, mt = xrow >> 4;
    #pragma unroll
    for (int oo = 0; oo < 2; ++oo){
      int o = xq*2 + oo, tkk = o >> 2, sl = (o & 3)*16 + m;
      *(short8*)&xs[0][((mt*8 + tkk)*64 + sl)*8] = *(short8*)&t[oo*8];
    }
  }
  __syncthreads();

  for (int k = 0; k < KK; ++k){
    const int cb  = k & 1;
    const int nbf = cb ^ 1;

    // stage x for step k+1 immediately (buffer free since end of step k-1)
    if (k < KK-1){
      const float4* p = (const float4*)(item + ((size_t)(nb + xrow)*KK + (k+1))*DD + xq*16);
      float4 a0 = p[0], a1 = p[1], a2 = p[2], a3 = p[3];
      unsigned short t[16];
      t[0]=f2bf(a0.x); t[1]=f2bf(a0.y); t[2]=f2bf(a0.z); t[3]=f2bf(a0.w);
      t[4]=f2bf(a1.x); t[5]=f2bf(a1.y); t[6]=f2bf(a1.z); t[7]=f2bf(a1.w);
      t[8]=f2bf(a2.x); t[9]=f2bf(a2.y); t[10]=f2bf(a2.z); t[11]=f2bf(a2.w);
      t[12]=f2bf(a3.x); t[13]=f2bf(a3.y); t[14]=f2bf(a3.z); t[15]=f2bf(a3.w);
      int m = xrow & 15, mt = xrow >> 4;
      #pragma unroll
      for (int oo = 0; oo < 2; ++oo){
        int o = xq*2 + oo, tkk = o >> 2, sl = (o & 3)*16 + m;
        *(short8*)&xs[nbf][((mt*8 + tkk)*64 + sl)*8] = *(short8*)&t[oo*8];
      }
    }

    // gi for this step: loop (mt, group) with a 12-reg accumulator
    #pragma unroll
    for (int mt = 0; mt < 2; ++mt)
      #pragma unroll
      for (int gg = 0; gg < 2; ++gg){
        f32x4 acc[3];
        #pragma unroll
        for (int gate = 0; gate < 3; ++gate){
          f32x4 z4 = {0.f,0.f,0.f,0.f};
          acc[gate] = z4;
        }
        #pragma unroll
        for (int tk = 0; tk < 8; ++tk){
          short8 ax = *(const short8*)&xs[cb][((mt*8 + tk)*64 + lane)*8];
          acc[0] = __builtin_amdgcn_mfma_f32_16x16x32_bf16(ax, W[gg][0][tk], acc[0], 0, 0, 0);
          acc[1] = __builtin_amdgcn_mfma_f32_16x16x32_bf16(ax, W[gg][1][tk], acc[1], 0, 0, 0);
          acc[2] = __builtin_amdgcn_mfma_f32_16x16x32_bf16(ax, W[gg][2][tk], acc[2], 0, 0, 0);
        }
        #pragma unroll
        for (int gate = 0; gate < 3; ++gate){
          uint2 pk;
          pk.x = packbf2(acc[gate][0], acc[gate][1]);
          pk.y = packbf2(acc[gate][2], acc[gate][3]);
          gi[(((size_t)blockIdx.x*KK + k)*6 + (mt*3 + gate))*1024 + (2*w + gg)*64 + lane] = pk;
        }
      }

    __syncthreads();
  }
}

// ---------------------------------------------------------------------------
// Kernel 3 (v2): recurrence. Whh streamed from L2 (384 KB/CU/step); gi DMA'd
// into LDS via global_load_lds (double-buffered, prefetched 1 step ahead) so
// NO extra VGPRs live across the MFMA loop (R7's spill fix).
// ---------------------------------------------------------------------------
__global__ __launch_bounds__(1024, 4) void gru_rec(
    const float* __restrict__ user,
    const float* __restrict__ b_ih, const float* __restrict__ b_hh,
    const float* __restrict__ w_out, const float* __restrict__ b_out,
    const int* __restrict__ length, const unsigned short* __restrict__ ws,
    const uint2* __restrict__ gi, float* __restrict__ out)
{
  __shared__ unsigned short hfrag[2][2*8*64*8];  // ping-pong, 32 KB
  __shared__ float yp[3][16][2][4][4];           // 6 KB
  __shared__ uint2 gis[2][6*1024];               // 96 KB gi double buffer

  const int tid  = threadIdx.x;
  const int lane = tid & 63;
  const int w    = tid >> 6;
  const int col  = lane & 15;
  const int q    = lane >> 4;
  const int nb   = blockIdx.x * ROWS;
  const int b    = nb / SS;

  const short8* fwh = (const short8*)ws + (FRAG_ELEMS/8);
  const char* gi_base = (const char*)gi + (size_t)blockIdx.x*KK*GI_STEP_BYTES;

  const int d    = w*16 + col;
  const float br_  = b_ih[d]       + b_hh[d];
  const float bz_  = b_ih[256 + d] + b_hh[256 + d];
  const float bin_ = b_ih[512 + d];
  const float bhn_ = b_hh[512 + d];
  const float wo_  = w_out[d];

  int idx = length[b] - 1; if (idx < 0) idx = 0;
  const float u0 = user[((size_t)b*SS + idx)*DD + d];
  float h[2][4];
  #pragma unroll
  for (int mt = 0; mt < 2; ++mt)
    #pragma unroll
    for (int reg = 0; reg < 4; ++reg)
      h[mt][reg] = u0;

  const int tkk = d >> 5;
  const int slb = ((d >> 3) & 3) * 16;
  const int dj  = d & 7;
  {
    unsigned short hb = f2bf(u0);
    #pragma unroll
    for (int mt = 0; mt < 2; ++mt)
      #pragma unroll
      for (int reg = 0; reg < 4; ++reg)
        hfrag[0][((mt*8 + tkk)*64 + slb + q*4 + reg)*8 + dj] = hb;
  }

  // DMA gi for step 0 into gis[0] (completes before the barrier below)
  #pragma unroll
  for (int c = 0; c < 3; ++c){
    int ch = w*3 + c;
    __builtin_amdgcn_global_load_lds(
      (const __attribute__((address_space(1))) unsigned int*)(gi_base + ch*1024 + lane*16),
      (__attribute__((address_space(3))) unsigned int*)((char*)&gis[0][0] + ch*1024),
      16, 0, 0);
  }
  __syncthreads();

  const float bout = b_out[0];

  for (int k = 0; k < KK; ++k){
    const int cb  = k & 1;
    const int nbf = cb ^ 1;

    // prefetch gi for step k+1 (target buffer last read at step k-1's gates)
    if (k < KK-1){
      const char* g = gi_base + (size_t)(k+1)*GI_STEP_BYTES;
      #pragma unroll
      for (int c = 0; c < 3; ++c){
        int ch = w*3 + c;
        __builtin_amdgcn_global_load_lds(
          (const __attribute__((address_space(1))) unsigned int*)(g + ch*1024 + lane*16),
          (__attribute__((address_space(3))) unsigned int*)((char*)&gis[nbf][0] + ch*1024),
          16, 0, 0);
      }
    }

    f32x4 gh[2][3];
    #pragma unroll
    for (int mt = 0; mt < 2; ++mt)
      #pragma unroll
      for (int gg = 0; gg < 3; ++gg){
        f32x4 z4 = {0.f,0.f,0.f,0.f};
        gh[mt][gg] = z4;
      }
    #pragma unroll
    for (int tk = 0; tk < 8; ++tk){
      short8 whr = fwh[((w     )*8 + tk)*64 + lane];
      short8 whz = fwh[((16 + w)*8 + tk)*64 + lane];
      short8 whn = fwh[((32 + w)*8 + tk)*64 + lane];
      short8 ah0 = *(const short8*)&hfrag[cb][((0*8 + tk)*64 + lane)*8];
      short8 ah1 = *(const short8*)&hfrag[cb][((1*8 + tk)*64 + lane)*8];
      gh[0][0] = __builtin_amdgcn_mfma_f32_16x16x32_bf16(ah0, whr, gh[0][0], 0, 0, 0);
      gh[1][0] = __builtin_amdgcn_mfma_f32_16x16x32_bf16(ah1, whr, gh[1][0], 0, 0, 0);
      gh[0][1] = __builtin_amdgcn_mfma_f32_16x16x32_bf16(ah0, whz, gh[0][1], 0, 0, 0);
      gh[1][1] = __builtin_amdgcn_mfma_f32_16x16x32_bf16(ah1, whz, gh[1][1], 0, 0, 0);
      gh[0][2] = __builtin_amdgcn_mfma_f32_16x16x32_bf16(ah0, whn, gh[0][2], 0, 0, 0);
      gh[1][2] = __builtin_amdgcn_mfma_f32_16x16x32_bf16(ah1, whn, gh[1][2], 0, 0, 0);
    }

    // gates: gi read from LDS (resident since end of step k-1)
    float ypl[2][4];
    #pragma unroll
    for (int mt = 0; mt < 2; ++mt){
      uint2 pr = gis[cb][(mt*3 + 0)*1024 + tid];
      uint2 pz = gis[cb][(mt*3 + 1)*1024 + tid];
      uint2 pn = gis[cb][(mt*3 + 2)*1024 + tid];
      #pragma unroll
      for (int reg = 0; reg < 4; ++reg){
        unsigned ur = (reg < 2) ? pr.x : pr.y;
        unsigned uz = (reg < 2) ? pz.x : pz.y;
        unsigned un = (reg < 2) ? pn.x : pn.y;
        float gir = (reg & 1) ? unpackhi(ur) : unpacklo(ur);
        float giz = (reg & 1) ? unpackhi(uz) : unpacklo(uz);
        float gin = (reg & 1) ? unpackhi(un) : unpacklo(un);
        float rp = gir + gh[mt][0][reg] + br_;
        float zp = giz + gh[mt][1][reg] + bz_;
        float r  = 1.f / (1.f + __expf(-rp));
        float z  = 1.f / (1.f + __expf(-zp));
        float np = gin + bin_ + r*(gh[mt][2][reg] + bhn_);
        np = fminf(fmaxf(np, -30.f), 30.f);
        float e  = __expf(2.f*np);
        float n  = (e - 1.f) / (e + 1.f);
        float hv = (1.f - z)*n + z*h[mt][reg];
        h[mt][reg] = hv;
        ypl[mt][reg] = hv * wo_;
      }
    }

    #pragma unroll
    for (int mt = 0; mt < 2; ++mt)
      #pragma unroll
      for (int reg = 0; reg < 4; ++reg){
        float p = ypl[mt][reg];
        p += __shfl_xor(p, 1);
        p += __shfl_xor(p, 2);
        p += __shfl_xor(p, 4);
        p += __shfl_xor(p, 8);
        if (col == 0) yp[k % 3][w][mt][q][reg] = p;
      }

    // h' -> hfrag[nbf]
    #pragma unroll
    for (int mt = 0; mt < 2; ++mt)
      #pragma unroll
      for (int reg = 0; reg < 4; ++reg)
        hfrag[nbf][((mt*8 + tkk)*64 + slb + q*4 + reg)*8 + dj] = f2bf(h[mt][reg]);

    // finalize y for step k-1
    if (k > 0 && tid < 32){
      float s = bout;
      #pragma unroll
      for (int ww = 0; ww < 16; ++ww)
        s += yp[(k-1) % 3][ww][tid >> 4][(tid >> 2) & 3][tid & 3];
      out[(size_t)(nb + tid)*KK + (k-1)] = s;
    }

    __syncthreads();   // orders LDS + drains gi DMA for step k+1
  }

  if (tid < 32){
    float s = bout;
    #pragma unroll
    for (int ww = 0; ww < 16; ++ww)
      s += yp[(KK-1) % 3][ww][tid >> 4][(tid >> 2) & 3][tid & 3];
    out[(size_t)(nb + tid)*KK + (KK-1)] = s;
  }
}

// ---------------------------------------------------------------------------
// Fallback: R3's verified single recurrent kernel (136 µs, no spill).
// ---------------------------------------------------------------------------
__global__ __launch_bounds__(1024, 4) void gru_fb(
    const float* __restrict__ item, const float* __restrict__ user,
    const float* __restrict__ b_ih, const float* __restrict__ b_hh,
    const float* __restrict__ w_out, const float* __restrict__ b_out,
    const int* __restrict__ length, const unsigned short* __restrict__ ws,
    float* __restrict__ out)
{
  __shared__ unsigned short xfrag[2][2*8*64*8];
  __shared__ unsigned short hfrag[2][2*8*64*8];
  __shared__ float yp[3][16][2][4][4];

  const int tid  = threadIdx.x;
  const int lane = tid & 63;
  const int w    = tid >> 6;
  const int col  = lane & 15;
  const int q    = lane >> 4;
  const int nb   = blockIdx.x * ROWS;
  const int b    = nb / SS;

  const short8* fw1 = (const short8*)ws;
  const short8* fwh = fw1 + (FRAG_ELEMS/8);

  const int d    = w*16 + col;
  const float br_  = b_ih[d]       + b_hh[d];
  const float bz_  = b_ih[256 + d] + b_hh[256 + d];
  const float bin_ = b_ih[512 + d];
  const float bhn_ = b_hh[512 + d];
  const float wo_  = w_out[d];

  int idx = length[b] - 1; if (idx < 0) idx = 0;
  const float u0 = user[((size_t)b*SS + idx)*DD + d];
  float h[2][4];
  #pragma unroll
  for (int mt = 0; mt < 2; ++mt)
    #pragma unroll
    for (int reg = 0; reg < 4; ++reg)
      h[mt][reg] = u0;

  const int tkk = d >> 5;
  const int slb = ((d >> 3) & 3) * 16;
  const int dj  = d & 7;
  {
    unsigned short hb = f2bf(u0);
    #pragma unroll
    for (int mt = 0; mt < 2; ++mt)
      #pragma unroll
      for (int reg = 0; reg < 4; ++reg)
        hfrag[0][((mt*8 + tkk)*64 + slb + q*4 + reg)*8 + dj] = hb;
  }

  const int xrow = tid >> 5;
  const int xo   = tid & 31;
  const int xmt  = xrow >> 4;
  const int xtk  = xo >> 2;
  const int xsl  = (xo & 3)*16 + (xrow & 15);
  {
    const float4* p = (const float4*)(item + ((size_t)(nb + xrow)*KK + 0)*DD + xo*8);
    float4 a0 = p[0], a1 = p[1];
    unsigned short t[8];
    t[0]=f2bf(a0.x); t[1]=f2bf(a0.y); t[2]=f2bf(a0.z); t[3]=f2bf(a0.w);
    t[4]=f2bf(a1.x); t[5]=f2bf(a1.y); t[6]=f2bf(a1.z); t[7]=f2bf(a1.w);
    *(short8*)&xfrag[0][((xmt*8 + xtk)*64 + xsl)*8] = *(short8*)t;
  }
  __syncthreads();

  const float bout = b_out[0];

  for (int k = 0; k < KK; ++k){
    const int cb  = k & 1;
    const int nbf = cb ^ 1;

    f32x4 acc[2][4];
    #pragma unroll
    for (int mt = 0; mt < 2; ++mt)
      #pragma unroll
      for (int kd = 0; kd < 4; ++kd){
        f32x4 z4 = {0.f, 0.f, 0.f, 0.f};
        acc[mt][kd] = z4;
      }

    #pragma unroll 2
    for (int tk = 0; tk < 8; ++tk){
      short8 ax0 = *(const short8*)&xfrag[cb][((0*8 + tk)*64 + lane)*8];
      short8 ax1 = *(const short8*)&xfrag[cb][((1*8 + tk)*64 + lane)*8];
      short8 ah0 = *(const short8*)&hfrag[cb][((0*8 + tk)*64 + lane)*8];
      short8 ah1 = *(const short8*)&hfrag[cb][((1*8 + tk)*64 + lane)*8];
      short8 w1r = fw1[((w     )*8 + tk)*64 + lane];
      short8 w1z = fw1[((16 + w)*8 + tk)*64 + lane];
      short8 w1n = fw1[((32 + w)*8 + tk)*64 + lane];
      short8 whr = fwh[((w     )*8 + tk)*64 + lane];
      short8 whz = fwh[((16 + w)*8 + tk)*64 + lane];
      short8 whn = fwh[((32 + w)*8 + tk)*64 + lane];
      acc[0][0] = __builtin_amdgcn_mfma_f32_16x16x32_bf16(ax0, w1r, acc[0][0], 0, 0, 0);
      acc[0][0] = __builtin_amdgcn_mfma_f32_16x16x32_bf16(ah0, whr, acc[0][0], 0, 0, 0);
      acc[0][1] = __builtin_amdgcn_mfma_f32_16x16x32_bf16(ax0, w1z, acc[0][1], 0, 0, 0);
      acc[0][1] = __builtin_amdgcn_mfma_f32_16x16x32_bf16(ah0, whz, acc[0][1], 0, 0, 0);
      acc[0][2] = __builtin_amdgcn_mfma_f32_16x16x32_bf16(ax0, w1n, acc[0][2], 0, 0, 0);
      acc[0][3] = __builtin_amdgcn_mfma_f32_16x16x32_bf16(ah0, whn, acc[0][3], 0, 0, 0);
      acc[1][0] = __builtin_amdgcn_mfma_f32_16x16x32_bf16(ax1, w1r, acc[1][0], 0, 0, 0);
      acc[1][0] = __builtin_amdgcn_mfma_f32_16x16x32_bf16(ah1, whr, acc[1][0], 0, 0, 0);
      acc[1][1] = __builtin_amdgcn_mfma_f32_16x16x32_bf16(ax1, w1z, acc[1][1], 0, 0, 0);
      acc[1][1] = __builtin_amdgcn_mfma_f32_16x16x32_bf16(ah1, whz, acc[1][1], 0, 0, 0);
      acc[1][2] = __builtin_amdgcn_mfma_f32_16x16x32_bf16(ax1, w1n, acc[1][2], 0, 0, 0);
      acc[1][3] = __builtin_amdgcn_mfma_f32_16x16x32_bf16(ah1, whn, acc[1][3], 0, 0, 0);
    }

    float4 xn0, xn1;
    if (k < KK-1){
      const float4* p = (const float4*)(item + ((size_t)(nb + xrow)*KK + (k+1))*DD + xo*8);
      xn0 = p[0]; xn1 = p[1];
    }

    float ypl[2][4];
    #pragma unroll
    for (int mt = 0; mt < 2; ++mt)
      #pragma unroll
      for (int reg = 0; reg < 4; ++reg){
        float rp = acc[mt][0][reg] + br_;
        float zp = acc[mt][1][reg] + bz_;
        float r  = 1.f / (1.f + __expf(-rp));
        float z  = 1.f / (1.f + __expf(-zp));
        float np = acc[mt][2][reg] + bin_ + r*(acc[mt][3][reg] + bhn_);
        np = fminf(fmaxf(np, -30.f), 30.f);
        float e  = __expf(2.f*np);
        float n  = (e - 1.f) / (e + 1.f);
        float hv = (1.f - z)*n + z*h[mt][reg];
        h[mt][reg] = hv;
        ypl[mt][reg] = hv * wo_;
      }

    #pragma unroll
    for (int mt = 0; mt < 2; ++mt)
      #pragma unroll
      for (int reg = 0; reg < 4; ++reg){
        float p = ypl[mt][reg];
        p += __shfl_xor(p, 1);
        p += __shfl_xor(p, 2);
        p += __shfl_xor(p, 4);
        p += __shfl_xor(p, 8);
        if (col == 0) yp[k % 3][w][mt][q][reg] = p;
      }

    #pragma unroll
    for (int mt = 0; mt < 2; ++mt)
      #pragma unroll
      for (int reg = 0; reg < 4; ++reg)
        hfrag[nbf][((mt*8 + tkk)*64 + slb + q*4 + reg)*8 + dj] = f2bf(h[mt][reg]);

    if (k < KK-1){
      unsigned short t[8];
      t[0]=f2bf(xn0.x); t[1]=f2bf(xn0.y); t[2]=f2bf(xn0.z); t[3]=f2bf(xn0.w);
      t[4]=f2bf(xn1.x); t[5]=f2bf(xn1.y); t[6]=f2bf(xn1.z); t[7]=f2bf(xn1.w);
      *(short8*)&xfrag[nbf][((xmt*8 + xtk)*64 + xsl)*8] = *(short8*)t;
    }

    if (k > 0 && tid < 32){
      float s = bout;
      #pragma unroll
      for (int ww = 0; ww < 16; ++ww)
        s += yp[(k-1) % 3][ww][tid >> 4][(tid >> 2) & 3][tid & 3];
      out[(size_t)(nb + tid)*KK + (k-1)] = s;
    }

    __syncthreads();
  }

  if (tid < 32){
    float s = bout;
    #pragma unroll
    for (int ww = 0; ww < 16; ++ww)
      s += yp[(KK-1) % 3][ww][tid >> 4][(tid >> 2) & 3][tid & 3];
    out[(size_t)(nb + tid)*KK + (KK-1)] = s;
  }
}

extern "C" void kernel_launch(void* const* d_in, const int* in_sizes, int n_in,
                              void* d_out, int out_size, void* d_ws, size_t ws_size,
                              hipStream_t stream) {
  const float* item   = (const float*)d_in[0];
  const float* user   = (const float*)d_in[1];
  const float* W_ih   = (const float*)d_in[2];
  const float* W_hh   = (const float*)d_in[3];
  const float* b_ih   = (const float*)d_in[4];
  const float* b_hh   = (const float*)d_in[5];
  const float* w_out  = (const float*)d_in[6];
  const float* b_out  = (const float*)d_in[7];
  const int*   length = (const int*)d_in[8];
  unsigned short* ws  = (unsigned short*)d_ws;
  float* out = (float*)d_out;

  hipLaunchKernelGGL(prep_weights, dim3((2*FRAG_ELEMS)/256), dim3(256), 0, stream,
                     W_ih, W_hh, ws);

  if (ws_size >= WS_NEED){
    uint2* gi = (uint2*)((char*)d_ws + WS_WBYTES);
    hipLaunchKernelGGL(gi_gemm, dim3(NBLK), dim3(512), 0, stream, item, ws, gi);
    hipLaunchKernelGGL(gru_rec, dim3(NBLK), dim3(1024), 0, stream,
                       user, b_ih, b_hh, w_out, b_out, length, ws, gi, out);
  } else {
    hipLaunchKernelGGL(gru_fb, dim3(NBLK), dim3(1024), 0, stream,
                       item, user, b_ih, b_hh, w_out, b_out, length, ws, out);
  }
}